// Round 12
// baseline (278.774 us; speedup 1.0000x reference)
//
#include <hip/hip_runtime.h>
#include <cstddef>

typedef unsigned short u16;
typedef __bf16 bf16x8 __attribute__((ext_vector_type(8)));
typedef float f32x4 __attribute__((ext_vector_type(4)));

// Problem constants
constexpr int B_   = 32;
constexpr int CTX_ = 128;
constexpr int NF_  = 128;     // frames
constexpr int NS_  = 32768;   // samples
constexpr int NE_  = 16;      // events
constexpr int CH_  = 256;
constexpr int NC_  = 257;     // coeffs
constexpr int TC_  = 514;     // 2*coeffs
constexpr int ROWS_ = B_ * NF_;  // 4096
constexpr int SEGM_ = 256;       // MLP pair-plane width
constexpr int K3IR_ = 960;       // 3*320 (logical triplet K, irfft)
constexpr int SEGI_ = 320;       // irfft pair-plane width (content 258/256 + zeros)
constexpr int PIRW_ = 2 * SEGI_; // 640 u16 per AB row
constexpr int PMLW_ = 2 * SEGM_; // 512 u16 per H row
constexpr float PI_ = 3.14159265358979323846f;

__device__ __forceinline__ float lrelu(float v) { return v > 0.f ? v : 0.2f * v; }
__device__ __forceinline__ u16 f2bf(float x) {
    unsigned u = __float_as_uint(x);
    return (u16)((u + 0x7FFFu + ((u >> 16) & 1u)) >> 16);
}
__device__ __forceinline__ float bf2f(u16 h) { return __uint_as_float(((unsigned)h) << 16); }

// ============ prep: table(pair,LUT) | compact | U | V ============
// [0,1280): irfft pair table  [1280,1792): tap compaction
// [1792,1824): U rows  [1824,1952): V rows
__global__ __launch_bounds__(256) void prep_kernel(
    const float* __restrict__ param, const float* __restrict__ pw,
    const float* __restrict__ pb, const float* __restrict__ pos,
    const float* __restrict__ w0, const float* __restrict__ times,
    u16* __restrict__ Tt, int* __restrict__ cnt, float2* __restrict__ taps,
    float* __restrict__ U, float* __restrict__ V)
{
    int blk = blockIdx.x;
    int tid = threadIdx.x;
    if (blk < 1280) {
        // ---- irfft pair table via 512-entry cos LUT ----
        __shared__ float lut[512];
        lut[tid]       = cosf((float)tid * (PI_ / 256.f));
        lut[tid + 256] = cosf((float)(tid + 256) * (PI_ / 256.f));
        __syncthreads();
        int idx = blk * 256 + tid;              // < 2*256*640
        int z = idx / (256 * PIRW_);
        int r = idx - z * (256 * PIRW_);
        int n = r / PIRW_, c = r - n * PIRW_;
        bool hiplane = c < SEGI_;
        int j = hiplane ? c : c - SEGI_;
        float val = 0.f;
        if (z == 0) {
            if (j < 129) {
                int k = 2 * j;
                float w = (k == 0 || k == 256) ? 1.f : 2.f;
                int m = (k * n) & 511;
                val = w * (1.f / 512.f) * lut[m];
            } else if (j < 258) {
                int kk = 2 * (j - 129);
                float w = (kk == 0 || kk == 256) ? 1.f : 2.f;
                int m = (kk * n) & 511;
                val = -w * (1.f / 512.f) * lut[(m - 128) & 511];   // sin
            }
        } else {
            if (j < 128) {
                int k = 2 * j + 1;
                int m = (k * n) & 511;
                val = 2.f * (1.f / 512.f) * lut[m];
            } else if (j < 256) {
                int kk = 2 * (j - 128) + 1;
                int m = (kk * n) & 511;
                val = -2.f * (1.f / 512.f) * lut[(m - 128) & 511]; // sin
            }
        }
        u16 h = f2bf(val);
        Tt[idx] = hiplane ? h : f2bf(val - bf2f(h));
    } else if (blk < 1792) {
        // ---- tap compaction ----
        int be = blk - 1280;
        __shared__ int c;
        if (tid == 0) c = 0;
        __syncthreads();
        if (tid < NF_) {
            float v = times[(size_t)be * NF_ + tid];
            if (v != 0.f) {
                int slot = atomicAdd(&c, 1);
                taps[(size_t)be * NF_ + slot] = make_float2((float)tid, v);
            }
        }
        __syncthreads();
        if (tid == 0) cnt[be] = c;
    } else if (blk < 1824) {
        // ---- U rows: recompute y0[b] in LDS, then U[b][n] = y0 . w0[n] ----
        int b = blk - 1792;      // 0..31
        __shared__ float ly[256];
        {
            const float* pr = param + b * CTX_;
            const float* wr = pw + tid * CTX_;
            float s = 0.f;
            #pragma unroll 4
            for (int j = 0; j < CTX_; ++j) s += pr[j] * wr[j];
            ly[tid] = s + pb[tid];
        }
        __syncthreads();
        {
            const float* wn = w0 + tid * CH_;
            float s = 0.f;
            #pragma unroll 4
            for (int c2 = 0; c2 < CH_; ++c2) s += ly[c2] * wn[c2];
            U[b * CH_ + tid] = s;
        }
    } else {
        // ---- V rows: V[f][n] = pos[f] . w0[n] ----
        int f = blk - 1824;      // 0..127
        const float* pf = pos + f * CH_;
        const float* wn = w0 + tid * CH_;
        float s = 0.f;
        #pragma unroll 4
        for (int c2 = 0; c2 < CH_; ++c2) s += pf[c2] * wn[c2];
        V[f * CH_ + tid] = s;
    }
}

// ---------------- mfgemmW: MLP GEMM, A/B synthesized during staging ----------------
// Logical triplet A=[Ah|Al|Ah], B=[Bh|Bh|Bl], SEG=256, K3=768, 12 K-steps.
// AFUSE=1: A row r built on the fly as lrelu(U[r>>7]+V[r&127]+b0) (fuse1 absorbed).
// AFUSE=0: A from bf16 pair buffer Ap [row][hi(256)|lo(256)].
// B always from fp32 weight Wg [NW][256]; rows >= NW are zero.
// Plane per K-step kt (compile-time): A: kt>>8==1 -> lo else hi; B: kt>>8==2 -> lo else hi.
// EPI 0: bias+lrelu -> bf16 pair (ldc=512); EPI 1: bias -> fp32 (N-guarded).
template<int EPI, bool AFUSE>
__global__ __launch_bounds__(128) void mfgemmW(
    const u16* __restrict__ Ap,
    const float* __restrict__ Ug, const float* __restrict__ Vg,
    const float* __restrict__ b0g,
    const float* __restrict__ Wg, int NW,
    const float* __restrict__ bias, void* __restrict__ Cout,
    int N, int ldc)
{
    constexpr int NSTEP = 12;
    const int tid = threadIdx.x;
    const int m0 = blockIdx.y * 32, n0 = blockIdx.x * 64;
    __shared__ __align__(16) u16 Als[2 * 32 * 64];   //  8KB
    __shared__ __align__(16) u16 Bls[2 * 64 * 64];   // 16KB
    const int sr = tid >> 2;
    const int sc = (tid & 3) * 16;
    const int xr = (sr & 7) << 4;
    const int loA0 = sr * 128 + ((sc * 2) ^ xr);
    const int loA1 = sr * 128 + ((sc * 2 + 16) ^ xr);
    const int loB2 = (sr + 32) * 128 + ((sc * 2) ^ xr);
    const int loB3 = (sr + 32) * 128 + ((sc * 2 + 16) ^ xr);
    const int wv = tid >> 6, lane = tid & 63;
    const int wc = wv * 32;
    const int lr = lane & 15;
    const int lkb = (lane >> 4) * 16;
    const int xf = (lr & 7) << 4;
    const int raf0 = lr * 128, raf1 = (16 + lr) * 128;
    const int rbf0 = (wc + lr) * 128, rbf1 = (wc + 16 + lr) * 128;
    f32x4 acc00 = {0.f, 0.f, 0.f, 0.f}, acc01 = acc00, acc10 = acc00, acc11 = acc00;

    // A sources
    const u16* ga = Ap + (size_t)(m0 + sr) * PMLW_ + sc;          // AFUSE=0
    const float* Uptr = Ug + ((m0 + sr) >> 7) * CH_;              // AFUSE=1
    const float* Vptr = Vg + ((m0 + sr) & 127) * CH_;
    // B sources (fp32 weights)
    const int nb0 = n0 + sr, nb1 = n0 + 32 + sr;
    const float* wb0 = Wg + (size_t)nb0 * 256;
    const float* wb1 = Wg + (size_t)nb1 * 256;
    const bool v0 = nb0 < NW, v1 = nb1 < NW;

    // raw register sets (depth-1 prefetch)
    uint4 apr0, apr1;            // AFUSE=0
    float4 au[4], av[4], ab4[4]; // AFUSE=1
    float4 bw0[4], bw1[4];

    auto fetchAll = [&](int kt) {
        int ch = (kt & 255) + sc;
        if (AFUSE) {
            #pragma unroll
            for (int g = 0; g < 4; ++g) {
                au[g]  = *(const float4*)(Uptr + ch + 4 * g);
                av[g]  = *(const float4*)(Vptr + ch + 4 * g);
                ab4[g] = *(const float4*)(b0g + ch + 4 * g);
            }
        } else {
            int a = (kt >= 512) ? kt - 512 : kt;   // [hi|lo|hi] -> pair offset
            apr0 = *(const uint4*)(ga + a);
            apr1 = *(const uint4*)(ga + a + 8);
        }
        float4 z = make_float4(0.f, 0.f, 0.f, 0.f);
        #pragma unroll
        for (int g = 0; g < 4; ++g) {
            bw0[g] = v0 ? *(const float4*)(wb0 + ch + 4 * g) : z;
            bw1[g] = v1 ? *(const float4*)(wb1 + ch + 4 * g) : z;
        }
    };
    auto cvt4 = [](const float4& w, bool lo, u16* t) {
        float x[4] = {w.x, w.y, w.z, w.w};
        #pragma unroll
        for (int c = 0; c < 4; ++c) {
            u16 h = f2bf(x[c]);
            t[c] = lo ? f2bf(x[c] - bf2f(h)) : h;
        }
    };
    auto stage = [&](int p, int kt) {
        char* ab = (char*)Als + p * 4096;
        char* bb = (char*)Bls + p * 8192;
        if (AFUSE) {
            bool alo = (kt >> 8) == 1;
            u16 t[16];
            #pragma unroll
            for (int g = 0; g < 4; ++g) {
                float4 s4 = make_float4(au[g].x + av[g].x + ab4[g].x,
                                        au[g].y + av[g].y + ab4[g].y,
                                        au[g].z + av[g].z + ab4[g].z,
                                        au[g].w + av[g].w + ab4[g].w);
                s4.x = lrelu(s4.x); s4.y = lrelu(s4.y);
                s4.z = lrelu(s4.z); s4.w = lrelu(s4.w);
                cvt4(s4, alo, t + 4 * g);
            }
            *(uint4*)(ab + loA0) = ((const uint4*)t)[0];
            *(uint4*)(ab + loA1) = ((const uint4*)t)[1];
        } else {
            *(uint4*)(ab + loA0) = apr0;
            *(uint4*)(ab + loA1) = apr1;
        }
        bool blo = (kt >> 8) == 2;
        u16 tb[16];
        #pragma unroll
        for (int g = 0; g < 4; ++g) cvt4(bw0[g], blo, tb + 4 * g);
        *(uint4*)(bb + loA0) = ((const uint4*)tb)[0];
        *(uint4*)(bb + loA1) = ((const uint4*)tb)[1];
        #pragma unroll
        for (int g = 0; g < 4; ++g) cvt4(bw1[g], blo, tb + 4 * g);
        *(uint4*)(bb + loB2) = ((const uint4*)tb)[0];
        *(uint4*)(bb + loB3) = ((const uint4*)tb)[1];
    };
    auto compute = [&](int p) {
        const char* pa = (const char*)Als + p * 4096;
        const char* pb = (const char*)Bls + p * 8192;
        #pragma unroll
        for (int s = 0; s < 2; ++s) {
            int kb = (s * 64 + lkb) ^ xf;
            bf16x8 a0 = *(const bf16x8*)(pa + raf0 + kb);
            bf16x8 a1 = *(const bf16x8*)(pa + raf1 + kb);
            bf16x8 b0 = *(const bf16x8*)(pb + rbf0 + kb);
            bf16x8 b1 = *(const bf16x8*)(pb + rbf1 + kb);
            acc00 = __builtin_amdgcn_mfma_f32_16x16x32_bf16(a0, b0, acc00, 0, 0, 0);
            acc01 = __builtin_amdgcn_mfma_f32_16x16x32_bf16(a0, b1, acc01, 0, 0, 0);
            acc10 = __builtin_amdgcn_mfma_f32_16x16x32_bf16(a1, b0, acc10, 0, 0, 0);
            acc11 = __builtin_amdgcn_mfma_f32_16x16x32_bf16(a1, b1, acc11, 0, 0, 0);
        }
    };

    fetchAll(0);
    int p = 0;
    #pragma unroll
    for (int i = 0; i < NSTEP; ++i) {
        int kt = i * 64;
        stage(p, kt);
        __syncthreads();
        if (i + 1 < NSTEP) fetchAll((i + 1) * 64);
        compute(p);
        p ^= 1;
    }
    const int er = (lane >> 4) * 4;
    const int ec = lane & 15;
    auto emit = [&](const f32x4& A, int mi, int ni) {
        #pragma unroll
        for (int r = 0; r < 4; ++r) {
            int m = m0 + mi * 16 + er + r;
            int n = n0 + wc + ni * 16 + ec;
            float v = A[r];
            if (EPI == 0) {
                v = lrelu(v + bias[n]);
                u16 h = f2bf(v);
                u16* p2 = (u16*)Cout + (size_t)m * ldc + n;
                p2[0] = h; p2[256] = f2bf(v - bf2f(h));
            } else {
                if (n < N) ((float*)Cout)[(size_t)m * ldc + n] = v + bias[n];
            }
        }
    };
    emit(acc00, 0, 0); emit(acc01, 0, 1); emit(acc10, 1, 0); emit(acc11, 1, 1);
}

// ---------------- mfgemm (irfft): C = A3 @ B3^T on PAIR buffers, unchanged ----------
template<int K3, int SEG>
__global__ __launch_bounds__(128) void mfgemm(
    const u16* __restrict__ A3, const u16* __restrict__ B3,
    void* __restrict__ Cout,
    int lda, int ldb, int ldc,
    size_t sAz, size_t sBz, size_t sCz)
{
    constexpr int NSTEP = K3 / 64;
    A3 += (size_t)blockIdx.z * sAz;
    B3 += (size_t)blockIdx.z * sBz;
    const int tid = threadIdx.x;
    const int m0 = blockIdx.y * 32, n0 = blockIdx.x * 64;
    __shared__ __align__(16) u16 Als[2 * 32 * 64];
    __shared__ __align__(16) u16 Bls[2 * 64 * 64];
    const int sr = tid >> 2;
    const int sc = (tid & 3) * 16;
    const u16* ga  = A3 + (size_t)(m0 + sr) * lda + sc;
    const u16* gb0 = B3 + (size_t)(n0 + sr) * ldb + sc;
    const u16* gb1 = B3 + (size_t)(n0 + 32 + sr) * ldb + sc;
    const int xr = (sr & 7) << 4;
    const int loA0 = sr * 128 + ((sc * 2) ^ xr);
    const int loA1 = sr * 128 + ((sc * 2 + 16) ^ xr);
    const int loB2 = (sr + 32) * 128 + ((sc * 2) ^ xr);
    const int loB3 = (sr + 32) * 128 + ((sc * 2 + 16) ^ xr);
    const int wv = tid >> 6, lane = tid & 63;
    const int wc = wv * 32;
    const int lr = lane & 15;
    const int lkb = (lane >> 4) * 16;
    const int xf = (lr & 7) << 4;
    const int raf0 = lr * 128, raf1 = (16 + lr) * 128;
    const int rbf0 = (wc + lr) * 128, rbf1 = (wc + 16 + lr) * 128;
    f32x4 acc00 = {0.f, 0.f, 0.f, 0.f}, acc01 = acc00, acc10 = acc00, acc11 = acc00;

    uint4 pa0, pa1, pb0, pb1, pb2, pb3;
    uint4 qa0, qa1, qb0, qb1, qb2, qb3;
    auto kA = [](int kt) { return kt >= 2 * SEG ? kt - 2 * SEG : kt; };
    auto kB = [](int kt) { return kt >= SEG ? kt - SEG : kt; };
    auto loadP = [&](int kt) {
        int a = kA(kt), b = kB(kt);
        pa0 = *(const uint4*)(ga + a);  pa1 = *(const uint4*)(ga + a + 8);
        pb0 = *(const uint4*)(gb0 + b); pb1 = *(const uint4*)(gb0 + b + 8);
        pb2 = *(const uint4*)(gb1 + b); pb3 = *(const uint4*)(gb1 + b + 8);
    };
    auto loadQ = [&](int kt) {
        int a = kA(kt), b = kB(kt);
        qa0 = *(const uint4*)(ga + a);  qa1 = *(const uint4*)(ga + a + 8);
        qb0 = *(const uint4*)(gb0 + b); qb1 = *(const uint4*)(gb0 + b + 8);
        qb2 = *(const uint4*)(gb1 + b); qb3 = *(const uint4*)(gb1 + b + 8);
    };
    auto compute = [&](int p) {
        const char* pa = (const char*)Als + p * 4096;
        const char* pb = (const char*)Bls + p * 8192;
        #pragma unroll
        for (int s = 0; s < 2; ++s) {
            int kb = (s * 64 + lkb) ^ xf;
            bf16x8 a0 = *(const bf16x8*)(pa + raf0 + kb);
            bf16x8 a1 = *(const bf16x8*)(pa + raf1 + kb);
            bf16x8 b0 = *(const bf16x8*)(pb + rbf0 + kb);
            bf16x8 b1 = *(const bf16x8*)(pb + rbf1 + kb);
            acc00 = __builtin_amdgcn_mfma_f32_16x16x32_bf16(a0, b0, acc00, 0, 0, 0);
            acc01 = __builtin_amdgcn_mfma_f32_16x16x32_bf16(a0, b1, acc01, 0, 0, 0);
            acc10 = __builtin_amdgcn_mfma_f32_16x16x32_bf16(a1, b0, acc10, 0, 0, 0);
            acc11 = __builtin_amdgcn_mfma_f32_16x16x32_bf16(a1, b1, acc11, 0, 0, 0);
        }
    };
    auto stage = [&](int p, const uint4& a0, const uint4& a1, const uint4& b0,
                     const uint4& b1, const uint4& b2, const uint4& b3) {
        char* ab = (char*)Als + p * 4096;
        char* bb = (char*)Bls + p * 8192;
        *(uint4*)(ab + loA0) = a0; *(uint4*)(ab + loA1) = a1;
        *(uint4*)(bb + loA0) = b0; *(uint4*)(bb + loA1) = b1;
        *(uint4*)(bb + loB2) = b2; *(uint4*)(bb + loB3) = b3;
    };
    loadP(0);
    if (NSTEP > 1) loadQ(64);
    int p = 0;
    #pragma unroll
    for (int i = 0; i < NSTEP; ++i) {
        if ((i & 1) == 0) {
            stage(p, pa0, pa1, pb0, pb1, pb2, pb3);
            __syncthreads();
            if (i + 2 < NSTEP) loadP((i + 2) * 64);
            compute(p);
        } else {
            stage(p, qa0, qa1, qb0, qb1, qb2, qb3);
            __syncthreads();
            if (i + 2 < NSTEP) loadQ((i + 2) * 64);
            compute(p);
        }
        p ^= 1;
    }
    const int er = (lane >> 4) * 4;
    const int ec = lane & 15;
    auto emit = [&](const f32x4& A, int mi, int ni) {
        #pragma unroll
        for (int r = 0; r < 4; ++r) {
            int m = m0 + mi * 16 + er + r;
            int n = n0 + wc + ni * 16 + ec;
            float* cf = (float*)Cout + (size_t)blockIdx.z * sCz;
            cf[(size_t)m * ldc + n] = A[r];
        }
    };
    emit(acc00, 0, 0); emit(acc01, 0, 1); emit(acc10, 1, 0); emit(acc11, 1, 1);
}

// ---------------- fused scan (unchanged from R11) ----------------
__global__ __launch_bounds__(256) void scanf_kernel(
    const float* __restrict__ raw, const float* __restrict__ noise,
    u16* __restrict__ ABe, u16* __restrict__ ABo)
{
    int b = blockIdx.x;
    int kg = blockIdx.y;
    int tid = threadIdx.x;
    int kl = tid & 15;
    int chunk = tid >> 4;
    bool active;
    int k;
    if (kg < 16) { k = kg * 16 + kl; active = true; }
    else         { k = 256;          active = (kl == 0); }

    __shared__ double ss[256];
    float dj[8], mj[8];
    double s = 0.0;
    float kf = (float)k * (PI_ / 256.f);
    int f0 = chunk * 8;
    if (active) {
        #pragma unroll
        for (int j = 0; j < 8; ++j) {
            size_t row = (size_t)(b * NF_ + f0 + j);
            float2 v = *(const float2*)(raw + row * TC_ + 2 * k);
            dj[j] = (1.f + v.y * noise[row * NC_ + k]) * kf;
            mj[j] = fabsf(v.x);
            s += (double)dj[j];
        }
    }
    ss[tid] = s;
    __syncthreads();
    if (active) {
        double p = 0.0;
        for (int cc = 0; cc < chunk; ++cc)
            p += ss[cc * 16 + kl];           // serial, order-preserving prefix
        int half = k >> 1;
        bool even = (k & 1) == 0;
        int ccol = half;
        int scol = even ? (129 + half) : (128 + half);
        u16* dst = even ? ABe : ABo;
        #pragma unroll
        for (int j = 0; j < 8; ++j) {
            p += (double)dj[j];
            float sn, cs;
            sincosf((float)p, &sn, &cs);
            float a = mj[j] * cs, bb = mj[j] * sn;
            u16* pr = dst + (size_t)(b * NF_ + f0 + j) * PIRW_;
            u16 ha = f2bf(a);
            pr[ccol] = ha; pr[SEGI_ + ccol] = f2bf(a - bf2f(ha));
            u16 hb = f2bf(bb);
            pr[scol] = hb; pr[SEGI_ + scol] = f2bf(bb - bf2f(hb));
        }
    } else {
        int t = chunk * 15 + kl - 1;        // 0..239
        for (int idx = t; idx < 252; idx += 240) {
            int col;
            u16* base;
            if (idx < 62)       { col = 258 + idx;                 base = ABe; }
            else if (idx < 124) { col = SEGI_ + 258 + (idx - 62);  base = ABe; }
            else if (idx < 188) { col = 256 + (idx - 124);         base = ABo; }
            else                { col = SEGI_ + 256 + (idx - 188); base = ABo; }
            for (int f = 0; f < NF_; ++f)
                base[(size_t)(b * NF_ + f) * PIRW_ + col] = 0;
        }
    }
}

// ---------------- conv2: sparse conv with inline OLA (unchanged from R11) ---------
__global__ __launch_bounds__(256) void conv2_kernel(const float* __restrict__ E,
                                                    const float* __restrict__ O,
                                                    const int* __restrict__ cnt,
                                                    const float2* __restrict__ taps,
                                                    float* __restrict__ out) {
    int be = blockIdx.y;
    int b = be >> 4;
    int n = cnt[be];
    int t = blockIdx.x * 2048 + (int)threadIdx.x * 8;
    int r0 = t & 255;
    float hr[8], hr2[8];
    #pragma unroll
    for (int j = 0; j < 8; ++j) {
        float cj = cosf((float)(r0 + j) * (PI_ / 256.f));
        hr[j]  = 0.5f - 0.5f * cj;
        hr2[j] = 0.5f + 0.5f * cj;
    }
    float acc[8] = {};
    for (int i = 0; i < n; ++i) {
        float2 ka = taps[(size_t)be * NF_ + i];
        int s0 = t - ((int)ka.x << 8);
        if (s0 < 0) continue;
        float amp = ka.y;
        int q = s0 >> 8;
        size_t row = (size_t)(b * NF_ + q) * 256 + r0;
        float4 e0 = *(const float4*)(E + row);
        float4 e1 = *(const float4*)(E + row + 4);
        float4 o0 = *(const float4*)(O + row);
        float4 o1 = *(const float4*)(O + row + 4);
        float sv[8];
        sv[0] = hr[0] * (e0.x + o0.x); sv[1] = hr[1] * (e0.y + o0.y);
        sv[2] = hr[2] * (e0.z + o0.z); sv[3] = hr[3] * (e0.w + o0.w);
        sv[4] = hr[4] * (e1.x + o1.x); sv[5] = hr[5] * (e1.y + o1.y);
        sv[6] = hr[6] * (e1.z + o1.z); sv[7] = hr[7] * (e1.w + o1.w);
        if (q > 0) {
            float4 pe0 = *(const float4*)(E + row - 256);
            float4 pe1 = *(const float4*)(E + row - 252);
            float4 po0 = *(const float4*)(O + row - 256);
            float4 po1 = *(const float4*)(O + row - 252);
            sv[0] += hr2[0] * (pe0.x - po0.x); sv[1] += hr2[1] * (pe0.y - po0.y);
            sv[2] += hr2[2] * (pe0.z - po0.z); sv[3] += hr2[3] * (pe0.w - po0.w);
            sv[4] += hr2[4] * (pe1.x - po1.x); sv[5] += hr2[5] * (pe1.y - po1.y);
            sv[6] += hr2[6] * (pe1.z - po1.z); sv[7] += hr2[7] * (pe1.w - po1.w);
        }
        #pragma unroll
        for (int j = 0; j < 8; ++j) acc[j] += amp * sv[j];
    }
    float* op = out + (size_t)be * NS_ + t;
    *(float4*)op = make_float4(acc[0], acc[1], acc[2], acc[3]);
    *(float4*)(op + 4) = make_float4(acc[4], acc[5], acc[6], acc[7]);
}

extern "C" void kernel_launch(void* const* d_in, const int* in_sizes, int n_in,
                              void* d_out, int out_size, void* d_ws, size_t ws_size,
                              hipStream_t stream) {
    const float* param  = (const float*)d_in[0];
    const float* times  = (const float*)d_in[1];
    const float* noise  = (const float*)d_in[2];
    const float* pos    = (const float*)d_in[3];
    const float* proj_w = (const float*)d_in[4];
    const float* proj_b = (const float*)d_in[5];
    const float* w0 = (const float*)d_in[6];
    const float* b0 = (const float*)d_in[7];
    const float* w1 = (const float*)d_in[8];
    const float* b1 = (const float*)d_in[9];
    const float* w2 = (const float*)d_in[10];
    const float* b2 = (const float*)d_in[11];
    const float* w_out = (const float*)d_in[12];
    const float* b_out = (const float*)d_in[13];
    float* out = (float*)d_out;
    float* ws = (float*)d_ws;

    // ws layout — cursor in FLOAT units; u16 buffers consume (u16_count/2) floats.
    constexpr size_t U_F    = 32 * 256;
    constexpr size_t V_F    = 128 * 256;
    constexpr size_t HP_F   = (size_t)ROWS_ * PMLW_ / 2;    // 1,048,576 per buffer
    constexpr size_t RAW_F  = (size_t)ROWS_ * TC_;          // 2,105,344
    constexpr size_t ABP_F  = 2 * (size_t)ROWS_ * PIRW_ / 2;// 2,621,440
    constexpr size_t TTP_F  = 2 * (size_t)256 * PIRW_ / 2;  //   163,840
    constexpr size_t EO_F   = 2 * (size_t)ROWS_ * 256;      // 2,097,152

    size_t cur = 0;
    float* U    = ws + cur;                 cur += U_F;
    float* V    = ws + cur;                 cur += V_F;
    u16*  H2p   = (u16*)(ws + cur);         cur += HP_F;
    u16*  H3p   = (u16*)(ws + cur);         cur += HP_F;
    float* RAW  = ws + cur;                 cur += RAW_F;
    u16*  ABP   = (u16*)(ws + cur);         cur += ABP_F;
    u16*  ABe   = ABP;
    u16*  ABo   = ABP + (size_t)ROWS_ * PIRW_;
    u16*  TTP   = (u16*)(ws + cur);         cur += TTP_F;
    float* EO   = ws + cur;                 cur += EO_F;
    int*   CNT  = (int*)(ws + cur);         cur += 512;
    float2* TAPS = (float2*)(ws + cur);     // 512*128 float2

    // 1) prep: pair table (LUT) + taps + U + V
    prep_kernel<<<1952, 256, 0, stream>>>(param, proj_w, proj_b, pos, w0, times,
                                          TTP, CNT, TAPS, U, V);
    // 2) L2: A fused from U,V,b0; B from w1 fp32 -> H2p pair
    mfgemmW<0, true><<<dim3(4, 128), 128, 0, stream>>>(nullptr, U, V, b0, w1, 256,
                                                       b1, H2p, 256, PMLW_);
    // 3) L3: A=H2p pair; B from w2 fp32 -> H3p pair
    mfgemmW<0, false><<<dim3(4, 128), 128, 0, stream>>>(H2p, nullptr, nullptr, nullptr,
                                                        w2, 256, b2, H3p, 256, PMLW_);
    // 4) OUT: A=H3p pair; B from w_out fp32 (NW=514) -> RAW fp32
    mfgemmW<1, false><<<dim3(9, 128), 128, 0, stream>>>(H3p, nullptr, nullptr, nullptr,
                                                        w_out, TC_, b_out, RAW, TC_, TC_);
    // 5) fused phase scan -> AB pair planes
    scanf_kernel<<<dim3(B_, 17), 256, 0, stream>>>(RAW, noise, ABe, ABo);
    // 6) parity irfft (z-batched): EO[z] = AB[z] @ Tt[z]^T
    mfgemm<K3IR_, SEGI_><<<dim3(4, 128, 2), 128, 0, stream>>>(ABP, TTP, EO,
                                                              PIRW_, PIRW_, 256,
                                                              (size_t)ROWS_ * PIRW_,
                                                              (size_t)256 * PIRW_,
                                                              (size_t)ROWS_ * 256);
    // 7) sparse conv with inline overlap-add/hann -> out
    dim3 gC(NS_ / 2048, B_ * NE_);
    conv2_kernel<<<gC, 256, 0, stream>>>(EO, EO + (size_t)ROWS_ * 256, CNT, TAPS, out);
}

// Round 13
// 278.248 us; speedup vs baseline: 1.0019x; 1.0019x over previous
//
#include <hip/hip_runtime.h>
#include <cstddef>

typedef unsigned short u16;
typedef unsigned int u32;
typedef __bf16 bf16x8 __attribute__((ext_vector_type(8)));
typedef float f32x4 __attribute__((ext_vector_type(4)));

// Problem constants
constexpr int B_   = 32;
constexpr int CTX_ = 128;
constexpr int NF_  = 128;     // frames
constexpr int NS_  = 32768;   // samples
constexpr int NE_  = 16;      // events
constexpr int CH_  = 256;
constexpr int NC_  = 257;     // coeffs
constexpr int TC_  = 514;     // 2*coeffs
constexpr int ROWS_ = B_ * NF_;  // 4096
constexpr int SEGM_ = 256;       // MLP pair-plane width
constexpr int K3IR_ = 960;       // 3*320 (logical triplet K, irfft)
constexpr int SEGI_ = 320;       // irfft pair-plane width (content 258/256 + zeros)
constexpr int PIRW_ = 2 * SEGI_; // 640 u16 per AB row
constexpr int PMLW_ = 2 * SEGM_; // 512 u16 per H row
constexpr float PI_ = 3.14159265358979323846f;

__device__ __forceinline__ float lrelu(float v) { return v > 0.f ? v : 0.2f * v; }
__device__ __forceinline__ u16 f2bf(float x) {
    unsigned u = __float_as_uint(x);
    return (u16)((u + 0x7FFFu + ((u >> 16) & 1u)) >> 16);
}
__device__ __forceinline__ float bf2f(u16 h) { return __uint_as_float(((unsigned)h) << 16); }
// pack two floats' bf16 (hi or lo residual plane) into one u32 (little-endian order)
__device__ __forceinline__ u32 pk2(float x, float y, bool lo) {
    u16 hx = f2bf(x), hy = f2bf(y);
    if (lo) { hx = f2bf(x - bf2f(hx)); hy = f2bf(y - bf2f(hy)); }
    return (u32)hx | ((u32)hy << 16);
}
__device__ __forceinline__ uint4 cvt8(const float4& a, const float4& b, bool lo) {
    return make_uint4(pk2(a.x, a.y, lo), pk2(a.z, a.w, lo),
                      pk2(b.x, b.y, lo), pk2(b.z, b.w, lo));
}

// ============ prep: table(pair,LUT) | compact | U | V ============
// [0,1280): irfft pair table  [1280,1792): tap compaction
// [1792,1824): U rows  [1824,1952): V rows
__global__ __launch_bounds__(256) void prep_kernel(
    const float* __restrict__ param, const float* __restrict__ pw,
    const float* __restrict__ pb, const float* __restrict__ pos,
    const float* __restrict__ w0, const float* __restrict__ times,
    u16* __restrict__ Tt, int* __restrict__ cnt, float2* __restrict__ taps,
    float* __restrict__ U, float* __restrict__ V)
{
    int blk = blockIdx.x;
    int tid = threadIdx.x;
    if (blk < 1280) {
        __shared__ float lut[512];
        lut[tid]       = cosf((float)tid * (PI_ / 256.f));
        lut[tid + 256] = cosf((float)(tid + 256) * (PI_ / 256.f));
        __syncthreads();
        int idx = blk * 256 + tid;              // < 2*256*640
        int z = idx / (256 * PIRW_);
        int r = idx - z * (256 * PIRW_);
        int n = r / PIRW_, c = r - n * PIRW_;
        bool hiplane = c < SEGI_;
        int j = hiplane ? c : c - SEGI_;
        float val = 0.f;
        if (z == 0) {
            if (j < 129) {
                int k = 2 * j;
                float w = (k == 0 || k == 256) ? 1.f : 2.f;
                int m = (k * n) & 511;
                val = w * (1.f / 512.f) * lut[m];
            } else if (j < 258) {
                int kk = 2 * (j - 129);
                float w = (kk == 0 || kk == 256) ? 1.f : 2.f;
                int m = (kk * n) & 511;
                val = -w * (1.f / 512.f) * lut[(m - 128) & 511];   // sin
            }
        } else {
            if (j < 128) {
                int k = 2 * j + 1;
                int m = (k * n) & 511;
                val = 2.f * (1.f / 512.f) * lut[m];
            } else if (j < 256) {
                int kk = 2 * (j - 128) + 1;
                int m = (kk * n) & 511;
                val = -2.f * (1.f / 512.f) * lut[(m - 128) & 511]; // sin
            }
        }
        u16 h = f2bf(val);
        Tt[idx] = hiplane ? h : f2bf(val - bf2f(h));
    } else if (blk < 1792) {
        int be = blk - 1280;
        __shared__ int c;
        if (tid == 0) c = 0;
        __syncthreads();
        if (tid < NF_) {
            float v = times[(size_t)be * NF_ + tid];
            if (v != 0.f) {
                int slot = atomicAdd(&c, 1);
                taps[(size_t)be * NF_ + slot] = make_float2((float)tid, v);
            }
        }
        __syncthreads();
        if (tid == 0) cnt[be] = c;
    } else if (blk < 1824) {
        int b = blk - 1792;      // 0..31
        __shared__ float ly[256];
        {
            const float* pr = param + b * CTX_;
            const float* wr = pw + tid * CTX_;
            float s = 0.f;
            #pragma unroll 4
            for (int j = 0; j < CTX_; ++j) s += pr[j] * wr[j];
            ly[tid] = s + pb[tid];
        }
        __syncthreads();
        {
            const float* wn = w0 + tid * CH_;
            float s = 0.f;
            #pragma unroll 4
            for (int c2 = 0; c2 < CH_; ++c2) s += ly[c2] * wn[c2];
            U[b * CH_ + tid] = s;
        }
    } else {
        int f = blk - 1824;      // 0..127
        const float* pf = pos + f * CH_;
        const float* wn = w0 + tid * CH_;
        float s = 0.f;
        #pragma unroll 4
        for (int c2 = 0; c2 < CH_; ++c2) s += pf[c2] * wn[c2];
        V[f * CH_ + tid] = s;
    }
}

// ---------------- mfgemmW: MLP GEMM, A/B synthesized during staging (register-only) --
// Logical triplet A=[Ah|Al|Ah], B=[Bh|Bh|Bl], SEG=256, K3=768, 12 K-steps.
// AFUSE=1: A row r = lrelu(U[r>>7]+V[r&127]+b0) built on the fly (fuse1 absorbed).
// AFUSE=0: A from bf16 pair buffer Ap [row][hi(256)|lo(256)].
// B from fp32 weights Wg [NW][256]; rows >= NW zero. All conversions via pk2/cvt8
// (pure scalar values -> no scratch arrays; R12's spill fixed).
// EPI 0: bias+lrelu -> bf16 pair (ldc=512); EPI 1: bias -> fp32 (N-guarded).
template<int EPI, bool AFUSE>
__global__ __launch_bounds__(128) void mfgemmW(
    const u16* __restrict__ Ap,
    const float* __restrict__ Ug, const float* __restrict__ Vg,
    const float* __restrict__ b0g,
    const float* __restrict__ Wg, int NW,
    const float* __restrict__ bias, void* __restrict__ Cout,
    int N, int ldc)
{
    constexpr int NSTEP = 12;
    const int tid = threadIdx.x;
    const int m0 = blockIdx.y * 32, n0 = blockIdx.x * 64;
    __shared__ __align__(16) u16 Als[2 * 32 * 64];   //  8KB
    __shared__ __align__(16) u16 Bls[2 * 64 * 64];   // 16KB
    const int sr = tid >> 2;
    const int sc = (tid & 3) * 16;
    const int xr = (sr & 7) << 4;
    const int loA0 = sr * 128 + ((sc * 2) ^ xr);
    const int loA1 = sr * 128 + ((sc * 2 + 16) ^ xr);
    const int loB2 = (sr + 32) * 128 + ((sc * 2) ^ xr);
    const int loB3 = (sr + 32) * 128 + ((sc * 2 + 16) ^ xr);
    const int wv = tid >> 6, lane = tid & 63;
    const int wc = wv * 32;
    const int lr = lane & 15;
    const int lkb = (lane >> 4) * 16;
    const int xf = (lr & 7) << 4;
    const int raf0 = lr * 128, raf1 = (16 + lr) * 128;
    const int rbf0 = (wc + lr) * 128, rbf1 = (wc + 16 + lr) * 128;
    f32x4 acc00 = {0.f, 0.f, 0.f, 0.f}, acc01 = acc00, acc10 = acc00, acc11 = acc00;

    // A sources
    const u16* ga = Ap + (size_t)(m0 + sr) * PMLW_ + sc;          // AFUSE=0
    const float* Uptr = Ug + ((m0 + sr) >> 7) * CH_;              // AFUSE=1
    const float* Vptr = Vg + ((m0 + sr) & 127) * CH_;
    // B sources (fp32 weights)
    const int nb0 = n0 + sr, nb1 = n0 + 32 + sr;
    const float* wb0 = Wg + (size_t)nb0 * 256;
    const float* wb1 = Wg + (size_t)nb1 * 256;
    const bool v0 = nb0 < NW, v1 = nb1 < NW;

    // named prefetch registers (depth-1)
    uint4 apr0, apr1;                              // AFUSE=0
    float4 as0, as1, as2, as3;                     // AFUSE=1 fused A (post-lrelu)
    float4 b00, b01, b02, b03, b10, b11, b12, b13; // B fp32

    const float4 z4 = make_float4(0.f, 0.f, 0.f, 0.f);
    auto fetchAll = [&](int kt) {
        int ch = (kt & 255) + sc;
        if (AFUSE) {
            const float4 u0 = *(const float4*)(Uptr + ch);
            const float4 u1 = *(const float4*)(Uptr + ch + 4);
            const float4 u2 = *(const float4*)(Uptr + ch + 8);
            const float4 u3 = *(const float4*)(Uptr + ch + 12);
            const float4 vv0 = *(const float4*)(Vptr + ch);
            const float4 vv1 = *(const float4*)(Vptr + ch + 4);
            const float4 vv2 = *(const float4*)(Vptr + ch + 8);
            const float4 vv3 = *(const float4*)(Vptr + ch + 12);
            const float4 c0 = *(const float4*)(b0g + ch);
            const float4 c1 = *(const float4*)(b0g + ch + 4);
            const float4 c2 = *(const float4*)(b0g + ch + 8);
            const float4 c3 = *(const float4*)(b0g + ch + 12);
            as0 = make_float4(lrelu(u0.x + vv0.x + c0.x), lrelu(u0.y + vv0.y + c0.y),
                              lrelu(u0.z + vv0.z + c0.z), lrelu(u0.w + vv0.w + c0.w));
            as1 = make_float4(lrelu(u1.x + vv1.x + c1.x), lrelu(u1.y + vv1.y + c1.y),
                              lrelu(u1.z + vv1.z + c1.z), lrelu(u1.w + vv1.w + c1.w));
            as2 = make_float4(lrelu(u2.x + vv2.x + c2.x), lrelu(u2.y + vv2.y + c2.y),
                              lrelu(u2.z + vv2.z + c2.z), lrelu(u2.w + vv2.w + c2.w));
            as3 = make_float4(lrelu(u3.x + vv3.x + c3.x), lrelu(u3.y + vv3.y + c3.y),
                              lrelu(u3.z + vv3.z + c3.z), lrelu(u3.w + vv3.w + c3.w));
        } else {
            int a = (kt >= 512) ? kt - 512 : kt;   // [hi|lo|hi] -> pair offset
            apr0 = *(const uint4*)(ga + a);
            apr1 = *(const uint4*)(ga + a + 8);
        }
        b00 = v0 ? *(const float4*)(wb0 + ch)      : z4;
        b01 = v0 ? *(const float4*)(wb0 + ch + 4)  : z4;
        b02 = v0 ? *(const float4*)(wb0 + ch + 8)  : z4;
        b03 = v0 ? *(const float4*)(wb0 + ch + 12) : z4;
        b10 = v1 ? *(const float4*)(wb1 + ch)      : z4;
        b11 = v1 ? *(const float4*)(wb1 + ch + 4)  : z4;
        b12 = v1 ? *(const float4*)(wb1 + ch + 8)  : z4;
        b13 = v1 ? *(const float4*)(wb1 + ch + 12) : z4;
    };
    auto stage = [&](int p, int kt) {
        char* ab = (char*)Als + p * 4096;
        char* bb = (char*)Bls + p * 8192;
        if (AFUSE) {
            bool alo = (kt >> 8) == 1;
            *(uint4*)(ab + loA0) = cvt8(as0, as1, alo);
            *(uint4*)(ab + loA1) = cvt8(as2, as3, alo);
        } else {
            *(uint4*)(ab + loA0) = apr0;
            *(uint4*)(ab + loA1) = apr1;
        }
        bool blo = (kt >> 8) == 2;
        *(uint4*)(bb + loA0) = cvt8(b00, b01, blo);
        *(uint4*)(bb + loA1) = cvt8(b02, b03, blo);
        *(uint4*)(bb + loB2) = cvt8(b10, b11, blo);
        *(uint4*)(bb + loB3) = cvt8(b12, b13, blo);
    };
    auto compute = [&](int p) {
        const char* pa = (const char*)Als + p * 4096;
        const char* pb = (const char*)Bls + p * 8192;
        #pragma unroll
        for (int s = 0; s < 2; ++s) {
            int kb = (s * 64 + lkb) ^ xf;
            bf16x8 a0 = *(const bf16x8*)(pa + raf0 + kb);
            bf16x8 a1 = *(const bf16x8*)(pa + raf1 + kb);
            bf16x8 b0 = *(const bf16x8*)(pb + rbf0 + kb);
            bf16x8 b1 = *(const bf16x8*)(pb + rbf1 + kb);
            acc00 = __builtin_amdgcn_mfma_f32_16x16x32_bf16(a0, b0, acc00, 0, 0, 0);
            acc01 = __builtin_amdgcn_mfma_f32_16x16x32_bf16(a0, b1, acc01, 0, 0, 0);
            acc10 = __builtin_amdgcn_mfma_f32_16x16x32_bf16(a1, b0, acc10, 0, 0, 0);
            acc11 = __builtin_amdgcn_mfma_f32_16x16x32_bf16(a1, b1, acc11, 0, 0, 0);
        }
    };

    fetchAll(0);
    int p = 0;
    #pragma unroll
    for (int i = 0; i < NSTEP; ++i) {
        int kt = i * 64;
        stage(p, kt);
        __syncthreads();
        if (i + 1 < NSTEP) fetchAll((i + 1) * 64);
        compute(p);
        p ^= 1;
    }
    const int er = (lane >> 4) * 4;
    const int ec = lane & 15;
    auto emit = [&](const f32x4& A, int mi, int ni) {
        #pragma unroll
        for (int r = 0; r < 4; ++r) {
            int m = m0 + mi * 16 + er + r;
            int n = n0 + wc + ni * 16 + ec;
            float v = A[r];
            if (EPI == 0) {
                v = lrelu(v + bias[n]);
                u16 h = f2bf(v);
                u16* p2 = (u16*)Cout + (size_t)m * ldc + n;
                p2[0] = h; p2[256] = f2bf(v - bf2f(h));
            } else {
                if (n < N) ((float*)Cout)[(size_t)m * ldc + n] = v + bias[n];
            }
        }
    };
    emit(acc00, 0, 0); emit(acc01, 0, 1); emit(acc10, 1, 0); emit(acc11, 1, 1);
}

// ---------------- mfgemm (irfft): C = A3 @ B3^T on PAIR buffers (R11, proven) --------
template<int K3, int SEG>
__global__ __launch_bounds__(128) void mfgemm(
    const u16* __restrict__ A3, const u16* __restrict__ B3,
    void* __restrict__ Cout,
    int lda, int ldb, int ldc,
    size_t sAz, size_t sBz, size_t sCz)
{
    constexpr int NSTEP = K3 / 64;
    A3 += (size_t)blockIdx.z * sAz;
    B3 += (size_t)blockIdx.z * sBz;
    const int tid = threadIdx.x;
    const int m0 = blockIdx.y * 32, n0 = blockIdx.x * 64;
    __shared__ __align__(16) u16 Als[2 * 32 * 64];
    __shared__ __align__(16) u16 Bls[2 * 64 * 64];
    const int sr = tid >> 2;
    const int sc = (tid & 3) * 16;
    const u16* ga  = A3 + (size_t)(m0 + sr) * lda + sc;
    const u16* gb0 = B3 + (size_t)(n0 + sr) * ldb + sc;
    const u16* gb1 = B3 + (size_t)(n0 + 32 + sr) * ldb + sc;
    const int xr = (sr & 7) << 4;
    const int loA0 = sr * 128 + ((sc * 2) ^ xr);
    const int loA1 = sr * 128 + ((sc * 2 + 16) ^ xr);
    const int loB2 = (sr + 32) * 128 + ((sc * 2) ^ xr);
    const int loB3 = (sr + 32) * 128 + ((sc * 2 + 16) ^ xr);
    const int wv = tid >> 6, lane = tid & 63;
    const int wc = wv * 32;
    const int lr = lane & 15;
    const int lkb = (lane >> 4) * 16;
    const int xf = (lr & 7) << 4;
    const int raf0 = lr * 128, raf1 = (16 + lr) * 128;
    const int rbf0 = (wc + lr) * 128, rbf1 = (wc + 16 + lr) * 128;
    f32x4 acc00 = {0.f, 0.f, 0.f, 0.f}, acc01 = acc00, acc10 = acc00, acc11 = acc00;

    uint4 pa0, pa1, pb0, pb1, pb2, pb3;
    uint4 qa0, qa1, qb0, qb1, qb2, qb3;
    auto kA = [](int kt) { return kt >= 2 * SEG ? kt - 2 * SEG : kt; };
    auto kB = [](int kt) { return kt >= SEG ? kt - SEG : kt; };
    auto loadP = [&](int kt) {
        int a = kA(kt), b = kB(kt);
        pa0 = *(const uint4*)(ga + a);  pa1 = *(const uint4*)(ga + a + 8);
        pb0 = *(const uint4*)(gb0 + b); pb1 = *(const uint4*)(gb0 + b + 8);
        pb2 = *(const uint4*)(gb1 + b); pb3 = *(const uint4*)(gb1 + b + 8);
    };
    auto loadQ = [&](int kt) {
        int a = kA(kt), b = kB(kt);
        qa0 = *(const uint4*)(ga + a);  qa1 = *(const uint4*)(ga + a + 8);
        qb0 = *(const uint4*)(gb0 + b); qb1 = *(const uint4*)(gb0 + b + 8);
        qb2 = *(const uint4*)(gb1 + b); qb3 = *(const uint4*)(gb1 + b + 8);
    };
    auto compute = [&](int p) {
        const char* pa = (const char*)Als + p * 4096;
        const char* pb = (const char*)Bls + p * 8192;
        #pragma unroll
        for (int s = 0; s < 2; ++s) {
            int kb = (s * 64 + lkb) ^ xf;
            bf16x8 a0 = *(const bf16x8*)(pa + raf0 + kb);
            bf16x8 a1 = *(const bf16x8*)(pa + raf1 + kb);
            bf16x8 b0 = *(const bf16x8*)(pb + rbf0 + kb);
            bf16x8 b1 = *(const bf16x8*)(pb + rbf1 + kb);
            acc00 = __builtin_amdgcn_mfma_f32_16x16x32_bf16(a0, b0, acc00, 0, 0, 0);
            acc01 = __builtin_amdgcn_mfma_f32_16x16x32_bf16(a0, b1, acc01, 0, 0, 0);
            acc10 = __builtin_amdgcn_mfma_f32_16x16x32_bf16(a1, b0, acc10, 0, 0, 0);
            acc11 = __builtin_amdgcn_mfma_f32_16x16x32_bf16(a1, b1, acc11, 0, 0, 0);
        }
    };
    auto stage = [&](int p, const uint4& a0, const uint4& a1, const uint4& b0,
                     const uint4& b1, const uint4& b2, const uint4& b3) {
        char* ab = (char*)Als + p * 4096;
        char* bb = (char*)Bls + p * 8192;
        *(uint4*)(ab + loA0) = a0; *(uint4*)(ab + loA1) = a1;
        *(uint4*)(bb + loA0) = b0; *(uint4*)(bb + loA1) = b1;
        *(uint4*)(bb + loB2) = b2; *(uint4*)(bb + loB3) = b3;
    };
    loadP(0);
    if (NSTEP > 1) loadQ(64);
    int p = 0;
    #pragma unroll
    for (int i = 0; i < NSTEP; ++i) {
        if ((i & 1) == 0) {
            stage(p, pa0, pa1, pb0, pb1, pb2, pb3);
            __syncthreads();
            if (i + 2 < NSTEP) loadP((i + 2) * 64);
            compute(p);
        } else {
            stage(p, qa0, qa1, qb0, qb1, qb2, qb3);
            __syncthreads();
            if (i + 2 < NSTEP) loadQ((i + 2) * 64);
            compute(p);
        }
        p ^= 1;
    }
    const int er = (lane >> 4) * 4;
    const int ec = lane & 15;
    auto emit = [&](const f32x4& A, int mi, int ni) {
        #pragma unroll
        for (int r = 0; r < 4; ++r) {
            int m = m0 + mi * 16 + er + r;
            int n = n0 + wc + ni * 16 + ec;
            float* cf = (float*)Cout + (size_t)blockIdx.z * sCz;
            cf[(size_t)m * ldc + n] = A[r];
        }
    };
    emit(acc00, 0, 0); emit(acc01, 0, 1); emit(acc10, 1, 0); emit(acc11, 1, 1);
}

// ---------------- fused scan (unchanged, proven) ----------------
__global__ __launch_bounds__(256) void scanf_kernel(
    const float* __restrict__ raw, const float* __restrict__ noise,
    u16* __restrict__ ABe, u16* __restrict__ ABo)
{
    int b = blockIdx.x;
    int kg = blockIdx.y;
    int tid = threadIdx.x;
    int kl = tid & 15;
    int chunk = tid >> 4;
    bool active;
    int k;
    if (kg < 16) { k = kg * 16 + kl; active = true; }
    else         { k = 256;          active = (kl == 0); }

    __shared__ double ss[256];
    float dj[8], mj[8];
    double s = 0.0;
    float kf = (float)k * (PI_ / 256.f);
    int f0 = chunk * 8;
    if (active) {
        #pragma unroll
        for (int j = 0; j < 8; ++j) {
            size_t row = (size_t)(b * NF_ + f0 + j);
            float2 v = *(const float2*)(raw + row * TC_ + 2 * k);
            dj[j] = (1.f + v.y * noise[row * NC_ + k]) * kf;
            mj[j] = fabsf(v.x);
            s += (double)dj[j];
        }
    }
    ss[tid] = s;
    __syncthreads();
    if (active) {
        double p = 0.0;
        for (int cc = 0; cc < chunk; ++cc)
            p += ss[cc * 16 + kl];           // serial, order-preserving prefix
        int half = k >> 1;
        bool even = (k & 1) == 0;
        int ccol = half;
        int scol = even ? (129 + half) : (128 + half);
        u16* dst = even ? ABe : ABo;
        #pragma unroll
        for (int j = 0; j < 8; ++j) {
            p += (double)dj[j];
            float sn, cs;
            sincosf((float)p, &sn, &cs);
            float a = mj[j] * cs, bb = mj[j] * sn;
            u16* pr = dst + (size_t)(b * NF_ + f0 + j) * PIRW_;
            u16 ha = f2bf(a);
            pr[ccol] = ha; pr[SEGI_ + ccol] = f2bf(a - bf2f(ha));
            u16 hb = f2bf(bb);
            pr[scol] = hb; pr[SEGI_ + scol] = f2bf(bb - bf2f(hb));
        }
    } else {
        int t = chunk * 15 + kl - 1;        // 0..239
        for (int idx = t; idx < 252; idx += 240) {
            int col;
            u16* base;
            if (idx < 62)       { col = 258 + idx;                 base = ABe; }
            else if (idx < 124) { col = SEGI_ + 258 + (idx - 62);  base = ABe; }
            else if (idx < 188) { col = 256 + (idx - 124);         base = ABo; }
            else                { col = SEGI_ + 256 + (idx - 188); base = ABo; }
            for (int f = 0; f < NF_; ++f)
                base[(size_t)(b * NF_ + f) * PIRW_ + col] = 0;
        }
    }
}

// ---------------- conv2: sparse conv with inline OLA (unchanged, proven) ---------
__global__ __launch_bounds__(256) void conv2_kernel(const float* __restrict__ E,
                                                    const float* __restrict__ O,
                                                    const int* __restrict__ cnt,
                                                    const float2* __restrict__ taps,
                                                    float* __restrict__ out) {
    int be = blockIdx.y;
    int b = be >> 4;
    int n = cnt[be];
    int t = blockIdx.x * 2048 + (int)threadIdx.x * 8;
    int r0 = t & 255;
    float hr[8], hr2[8];
    #pragma unroll
    for (int j = 0; j < 8; ++j) {
        float cj = cosf((float)(r0 + j) * (PI_ / 256.f));
        hr[j]  = 0.5f - 0.5f * cj;
        hr2[j] = 0.5f + 0.5f * cj;
    }
    float acc[8] = {};
    for (int i = 0; i < n; ++i) {
        float2 ka = taps[(size_t)be * NF_ + i];
        int s0 = t - ((int)ka.x << 8);
        if (s0 < 0) continue;
        float amp = ka.y;
        int q = s0 >> 8;
        size_t row = (size_t)(b * NF_ + q) * 256 + r0;
        float4 e0 = *(const float4*)(E + row);
        float4 e1 = *(const float4*)(E + row + 4);
        float4 o0 = *(const float4*)(O + row);
        float4 o1 = *(const float4*)(O + row + 4);
        float sv[8];
        sv[0] = hr[0] * (e0.x + o0.x); sv[1] = hr[1] * (e0.y + o0.y);
        sv[2] = hr[2] * (e0.z + o0.z); sv[3] = hr[3] * (e0.w + o0.w);
        sv[4] = hr[4] * (e1.x + o1.x); sv[5] = hr[5] * (e1.y + o1.y);
        sv[6] = hr[6] * (e1.z + o1.z); sv[7] = hr[7] * (e1.w + o1.w);
        if (q > 0) {
            float4 pe0 = *(const float4*)(E + row - 256);
            float4 pe1 = *(const float4*)(E + row - 252);
            float4 po0 = *(const float4*)(O + row - 256);
            float4 po1 = *(const float4*)(O + row - 252);
            sv[0] += hr2[0] * (pe0.x - po0.x); sv[1] += hr2[1] * (pe0.y - po0.y);
            sv[2] += hr2[2] * (pe0.z - po0.z); sv[3] += hr2[3] * (pe0.w - po0.w);
            sv[4] += hr2[4] * (pe1.x - po1.x); sv[5] += hr2[5] * (pe1.y - po1.y);
            sv[6] += hr2[6] * (pe1.z - po1.z); sv[7] += hr2[7] * (pe1.w - po1.w);
        }
        #pragma unroll
        for (int j = 0; j < 8; ++j) acc[j] += amp * sv[j];
    }
    float* op = out + (size_t)be * NS_ + t;
    *(float4*)op = make_float4(acc[0], acc[1], acc[2], acc[3]);
    *(float4*)(op + 4) = make_float4(acc[4], acc[5], acc[6], acc[7]);
}

extern "C" void kernel_launch(void* const* d_in, const int* in_sizes, int n_in,
                              void* d_out, int out_size, void* d_ws, size_t ws_size,
                              hipStream_t stream) {
    const float* param  = (const float*)d_in[0];
    const float* times  = (const float*)d_in[1];
    const float* noise  = (const float*)d_in[2];
    const float* pos    = (const float*)d_in[3];
    const float* proj_w = (const float*)d_in[4];
    const float* proj_b = (const float*)d_in[5];
    const float* w0 = (const float*)d_in[6];
    const float* b0 = (const float*)d_in[7];
    const float* w1 = (const float*)d_in[8];
    const float* b1 = (const float*)d_in[9];
    const float* w2 = (const float*)d_in[10];
    const float* b2 = (const float*)d_in[11];
    const float* w_out = (const float*)d_in[12];
    const float* b_out = (const float*)d_in[13];
    float* out = (float*)d_out;
    float* ws = (float*)d_ws;

    // ws layout — cursor in FLOAT units; u16 buffers consume (u16_count/2) floats.
    constexpr size_t U_F    = 32 * 256;
    constexpr size_t V_F    = 128 * 256;
    constexpr size_t HP_F   = (size_t)ROWS_ * PMLW_ / 2;    // 1,048,576 per buffer
    constexpr size_t RAW_F  = (size_t)ROWS_ * TC_;          // 2,105,344
    constexpr size_t ABP_F  = 2 * (size_t)ROWS_ * PIRW_ / 2;// 2,621,440
    constexpr size_t TTP_F  = 2 * (size_t)256 * PIRW_ / 2;  //   163,840
    constexpr size_t EO_F   = 2 * (size_t)ROWS_ * 256;      // 2,097,152

    size_t cur = 0;
    float* U    = ws + cur;                 cur += U_F;
    float* V    = ws + cur;                 cur += V_F;
    u16*  H2p   = (u16*)(ws + cur);         cur += HP_F;
    u16*  H3p   = (u16*)(ws + cur);         cur += HP_F;
    float* RAW  = ws + cur;                 cur += RAW_F;
    u16*  ABP   = (u16*)(ws + cur);         cur += ABP_F;
    u16*  ABe   = ABP;
    u16*  ABo   = ABP + (size_t)ROWS_ * PIRW_;
    u16*  TTP   = (u16*)(ws + cur);         cur += TTP_F;
    float* EO   = ws + cur;                 cur += EO_F;
    int*   CNT  = (int*)(ws + cur);         cur += 512;
    float2* TAPS = (float2*)(ws + cur);     // 512*128 float2

    // 1) prep: pair table (LUT) + taps + U + V
    prep_kernel<<<1952, 256, 0, stream>>>(param, proj_w, proj_b, pos, w0, times,
                                          TTP, CNT, TAPS, U, V);
    // 2) L2: A fused from U,V,b0; B from w1 fp32 -> H2p pair
    mfgemmW<0, true><<<dim3(4, 128), 128, 0, stream>>>(nullptr, U, V, b0, w1, 256,
                                                       b1, H2p, 256, PMLW_);
    // 3) L3: A=H2p pair; B from w2 fp32 -> H3p pair
    mfgemmW<0, false><<<dim3(4, 128), 128, 0, stream>>>(H2p, nullptr, nullptr, nullptr,
                                                        w2, 256, b2, H3p, 256, PMLW_);
    // 4) OUT: A=H3p pair; B from w_out fp32 (NW=514) -> RAW fp32
    mfgemmW<1, false><<<dim3(9, 128), 128, 0, stream>>>(H3p, nullptr, nullptr, nullptr,
                                                        w_out, TC_, b_out, RAW, TC_, TC_);
    // 5) fused phase scan -> AB pair planes
    scanf_kernel<<<dim3(B_, 17), 256, 0, stream>>>(RAW, noise, ABe, ABo);
    // 6) parity irfft (z-batched): EO[z] = AB[z] @ Tt[z]^T
    mfgemm<K3IR_, SEGI_><<<dim3(4, 128, 2), 128, 0, stream>>>(ABP, TTP, EO,
                                                              PIRW_, PIRW_, 256,
                                                              (size_t)ROWS_ * PIRW_,
                                                              (size_t)256 * PIRW_,
                                                              (size_t)ROWS_ * 256);
    // 7) sparse conv with inline overlap-add/hann -> out
    dim3 gC(NS_ / 2048, B_ * NE_);
    conv2_kernel<<<gC, 256, 0, stream>>>(EO, EO + (size_t)ROWS_ * 256, CNT, TAPS, out);
}

// Round 15
// 93.869 us; speedup vs baseline: 2.9698x; 2.9642x over previous
//
#include <hip/hip_runtime.h>
#include <cstddef>

typedef unsigned short u16;
typedef __bf16 bf16x8 __attribute__((ext_vector_type(8)));
typedef float f32x4 __attribute__((ext_vector_type(4)));

// Problem constants
constexpr int B_   = 32;
constexpr int CTX_ = 128;
constexpr int NF_  = 128;     // frames
constexpr int NS_  = 32768;   // samples
constexpr int NE_  = 16;      // events
constexpr int CH_  = 256;
constexpr int NC_  = 257;     // coeffs
constexpr int TC_  = 514;     // 2*coeffs
constexpr int ROWS_ = B_ * NF_;  // 4096
constexpr int K3MLP_ = 768;      // 3*256 (logical triplet K)
constexpr int SEGM_ = 256;       // MLP pair-plane width
constexpr int K3IR_ = 960;       // 3*320 (logical triplet K, irfft)
constexpr int SEGI_ = 320;       // irfft pair-plane width (content 258/256 + zeros)
constexpr int PIRW_ = 2 * SEGI_; // 640 u16 per AB row
constexpr int PMLW_ = 2 * SEGM_; // 512 u16 per H/W row
constexpr float PI_ = 3.14159265358979323846f;

__device__ __forceinline__ float lrelu(float v) { return v > 0.f ? v : 0.2f * v; }
__device__ __forceinline__ u16 f2bf(float x) {
    unsigned u = __float_as_uint(x);
    return (u16)((u + 0x7FFFu + ((u >> 16) & 1u)) >> 16);
}
__device__ __forceinline__ float bf2f(u16 h) { return __uint_as_float(((unsigned)h) << 16); }

// ============ prep: table(pair,LUT) | weights(pair) | compact | U | V ============
// [0,1280): irfft pair table  [1280,2368): weight pairs
// [2368,2880): tap compaction [2880,2912): U rows  [2912,3040): V rows
__global__ __launch_bounds__(256) void prep_kernel(
    const float* __restrict__ param, const float* __restrict__ pw,
    const float* __restrict__ pb, const float* __restrict__ pos,
    const float* __restrict__ w0, const float* __restrict__ w1,
    const float* __restrict__ w2, const float* __restrict__ wo,
    const float* __restrict__ times,
    u16* __restrict__ Tt, u16* __restrict__ W1p, u16* __restrict__ W2p,
    u16* __restrict__ WOp, int* __restrict__ cnt, float2* __restrict__ taps,
    float* __restrict__ U, float* __restrict__ V)
{
    int blk = blockIdx.x;
    int tid = threadIdx.x;
    if (blk < 1280) {
        // ---- irfft pair table via 512-entry cos LUT ----
        __shared__ float lut[512];
        lut[tid]       = cosf((float)tid * (PI_ / 256.f));
        lut[tid + 256] = cosf((float)(tid + 256) * (PI_ / 256.f));
        __syncthreads();
        int idx = blk * 256 + tid;              // < 2*256*640
        int z = idx / (256 * PIRW_);
        int r = idx - z * (256 * PIRW_);
        int n = r / PIRW_, c = r - n * PIRW_;
        bool hiplane = c < SEGI_;
        int j = hiplane ? c : c - SEGI_;
        float val = 0.f;
        if (z == 0) {
            if (j < 129) {
                int k = 2 * j;
                float w = (k == 0 || k == 256) ? 1.f : 2.f;
                int m = (k * n) & 511;
                val = w * (1.f / 512.f) * lut[m];
            } else if (j < 258) {
                int kk = 2 * (j - 129);
                float w = (kk == 0 || kk == 256) ? 1.f : 2.f;
                int m = (kk * n) & 511;
                val = -w * (1.f / 512.f) * lut[(m - 128) & 511];   // sin
            }
        } else {
            if (j < 128) {
                int k = 2 * j + 1;
                int m = (k * n) & 511;
                val = 2.f * (1.f / 512.f) * lut[m];
            } else if (j < 256) {
                int kk = 2 * (j - 128) + 1;
                int m = (kk * n) & 511;
                val = -2.f * (1.f / 512.f) * lut[(m - 128) & 511]; // sin
            }
        }
        u16 h = f2bf(val);
        Tt[idx] = hiplane ? h : f2bf(val - bf2f(h));
    } else if (blk < 2368) {
        // ---- weight pairs (hi|lo planar) ----
        int row = blk - 1280;        // 0..1087
        int k = tid;
        float v;
        u16* p;
        if (row < 256) {
            v = w1[row * 256 + k];
            p = W1p + (size_t)row * PMLW_;
        } else if (row < 512) {
            v = w2[(row - 256) * 256 + k];
            p = W2p + (size_t)(row - 256) * PMLW_;
        } else {
            int n = row - 512;       // 0..575, valid < 514
            v = (n < TC_) ? wo[n * 256 + k] : 0.f;
            p = WOp + (size_t)n * PMLW_;
        }
        u16 h = f2bf(v);
        p[k] = h; p[256 + k] = f2bf(v - bf2f(h));
    } else if (blk < 2880) {
        // ---- tap compaction ----
        int be = blk - 2368;
        __shared__ int c;
        if (tid == 0) c = 0;
        __syncthreads();
        if (tid < NF_) {
            float v = times[(size_t)be * NF_ + tid];
            if (v != 0.f) {
                int slot = atomicAdd(&c, 1);
                taps[(size_t)be * NF_ + slot] = make_float2((float)tid, v);
            }
        }
        __syncthreads();
        if (tid == 0) cnt[be] = c;
    } else if (blk < 2912) {
        // ---- U rows: recompute y0[b] in LDS, then U[b][n] = y0 . w0[n] ----
        int b = blk - 2880;      // 0..31
        __shared__ float ly[256];
        {
            const float* pr = param + b * CTX_;
            const float* wr = pw + tid * CTX_;
            float s = 0.f;
            #pragma unroll 4
            for (int j = 0; j < CTX_; ++j) s += pr[j] * wr[j];
            ly[tid] = s + pb[tid];
        }
        __syncthreads();
        {
            const float* wn = w0 + tid * CH_;
            float s = 0.f;
            #pragma unroll 4
            for (int c2 = 0; c2 < CH_; ++c2) s += ly[c2] * wn[c2];
            U[b * CH_ + tid] = s;
        }
    } else {
        // ---- V rows: V[f][n] = pos[f] . w0[n] ----
        int f = blk - 2912;      // 0..127
        const float* pf = pos + f * CH_;
        const float* wn = w0 + tid * CH_;
        float s = 0.f;
        #pragma unroll 4
        for (int c2 = 0; c2 < CH_; ++c2) s += pf[c2] * wn[c2];
        V[f * CH_ + tid] = s;
    }
}

// ---------------- fuse1: H1 pair = lrelu(U[b] + V[f] + b0) ----------------
__global__ void fuse1_kernel(const float* __restrict__ U, const float* __restrict__ V,
                             const float* __restrict__ b0, u16* __restrict__ Hp) {
    int idx = blockIdx.x * 256 + threadIdx.x;   // 4096*256
    int c = idx & 255;
    int row = idx >> 8;
    int b = row >> 7, f = row & 127;
    float v = lrelu(U[b * CH_ + c] + V[f * CH_ + c] + b0[c]);
    u16 h = f2bf(v);
    u16* p = Hp + (size_t)row * PMLW_;
    p[c] = h; p[256 + c] = f2bf(v - bf2f(h));
}

// ---------------- mfgemm: C = A3 @ B3^T, bf16-split MFMA on PAIR buffers ----------
// Logical triplet A=[Ah|Al|Ah], B=[Bh|Bh|Bl] with plane width SEG; global buffers
// store only [hi|lo]; prefetch offsets remapped at compile time:
//   kA(kt) = kt>=2*SEG ? kt-2*SEG : kt ;  kB(kt) = kt>=SEG ? kt-SEG : kt.
// 32x64 tile, 128 threads, depth-2 prefetch, double-buffered LDS (24KB).
// EPI 0: bias+lrelu -> bf16 pair (ldc=512); EPI 1: bias -> fp32 (N-guarded);
// EPI 2: plain fp32 (z-batched).
template<int EPI, int K3, int SEG>
__global__ __launch_bounds__(128) void mfgemm(
    const u16* __restrict__ A3, const u16* __restrict__ B3,
    const float* __restrict__ bias, void* __restrict__ Cout,
    int N, int lda, int ldb, int ldc,
    size_t sAz, size_t sBz, size_t sCz)
{
    constexpr int NSTEP = K3 / 64;
    A3 += (size_t)blockIdx.z * sAz;
    B3 += (size_t)blockIdx.z * sBz;
    const int tid = threadIdx.x;
    const int m0 = blockIdx.y * 32, n0 = blockIdx.x * 64;
    __shared__ __align__(16) u16 Als[2 * 32 * 64];   //  8KB
    __shared__ __align__(16) u16 Bls[2 * 64 * 64];   // 16KB
    const int sr = tid >> 2;
    const int sc = (tid & 3) * 16;
    const u16* ga  = A3 + (size_t)(m0 + sr) * lda + sc;
    const u16* gb0 = B3 + (size_t)(n0 + sr) * ldb + sc;
    const u16* gb1 = B3 + (size_t)(n0 + 32 + sr) * ldb + sc;
    const int xr = (sr & 7) << 4;
    const int loA0 = sr * 128 + ((sc * 2) ^ xr);
    const int loA1 = sr * 128 + ((sc * 2 + 16) ^ xr);
    const int loB2 = (sr + 32) * 128 + ((sc * 2) ^ xr);
    const int loB3 = (sr + 32) * 128 + ((sc * 2 + 16) ^ xr);
    const int wv = tid >> 6, lane = tid & 63;
    const int wc = wv * 32;
    const int lr = lane & 15;
    const int lkb = (lane >> 4) * 16;
    const int xf = (lr & 7) << 4;
    const int raf0 = lr * 128, raf1 = (16 + lr) * 128;
    const int rbf0 = (wc + lr) * 128, rbf1 = (wc + 16 + lr) * 128;
    f32x4 acc00 = {0.f, 0.f, 0.f, 0.f}, acc01 = acc00, acc10 = acc00, acc11 = acc00;

    uint4 pa0, pa1, pb0, pb1, pb2, pb3;   // set P
    uint4 qa0, qa1, qb0, qb1, qb2, qb3;   // set Q
    auto kA = [](int kt) { return kt >= 2 * SEG ? kt - 2 * SEG : kt; };
    auto kB = [](int kt) { return kt >= SEG ? kt - SEG : kt; };
    auto loadP = [&](int kt) {
        int a = kA(kt), b = kB(kt);
        pa0 = *(const uint4*)(ga + a);  pa1 = *(const uint4*)(ga + a + 8);
        pb0 = *(const uint4*)(gb0 + b); pb1 = *(const uint4*)(gb0 + b + 8);
        pb2 = *(const uint4*)(gb1 + b); pb3 = *(const uint4*)(gb1 + b + 8);
    };
    auto loadQ = [&](int kt) {
        int a = kA(kt), b = kB(kt);
        qa0 = *(const uint4*)(ga + a);  qa1 = *(const uint4*)(ga + a + 8);
        qb0 = *(const uint4*)(gb0 + b); qb1 = *(const uint4*)(gb0 + b + 8);
        qb2 = *(const uint4*)(gb1 + b); qb3 = *(const uint4*)(gb1 + b + 8);
    };
    auto compute = [&](int p) {
        const char* pa = (const char*)Als + p * 4096;
        const char* pb = (const char*)Bls + p * 8192;
        #pragma unroll
        for (int s = 0; s < 2; ++s) {
            int kb = (s * 64 + lkb) ^ xf;
            bf16x8 a0 = *(const bf16x8*)(pa + raf0 + kb);
            bf16x8 a1 = *(const bf16x8*)(pa + raf1 + kb);
            bf16x8 b0 = *(const bf16x8*)(pb + rbf0 + kb);
            bf16x8 b1 = *(const bf16x8*)(pb + rbf1 + kb);
            acc00 = __builtin_amdgcn_mfma_f32_16x16x32_bf16(a0, b0, acc00, 0, 0, 0);
            acc01 = __builtin_amdgcn_mfma_f32_16x16x32_bf16(a0, b1, acc01, 0, 0, 0);
            acc10 = __builtin_amdgcn_mfma_f32_16x16x32_bf16(a1, b0, acc10, 0, 0, 0);
            acc11 = __builtin_amdgcn_mfma_f32_16x16x32_bf16(a1, b1, acc11, 0, 0, 0);
        }
    };
    auto stage = [&](int p, const uint4& a0, const uint4& a1, const uint4& b0,
                     const uint4& b1, const uint4& b2, const uint4& b3) {
        char* ab = (char*)Als + p * 4096;
        char* bb = (char*)Bls + p * 8192;
        *(uint4*)(ab + loA0) = a0; *(uint4*)(ab + loA1) = a1;
        *(uint4*)(bb + loA0) = b0; *(uint4*)(bb + loA1) = b1;
        *(uint4*)(bb + loB2) = b2; *(uint4*)(bb + loB3) = b3;
    };
    loadP(0);
    if (NSTEP > 1) loadQ(64);
    int p = 0;
    #pragma unroll
    for (int i = 0; i < NSTEP; ++i) {
        if ((i & 1) == 0) {
            stage(p, pa0, pa1, pb0, pb1, pb2, pb3);
            __syncthreads();
            if (i + 2 < NSTEP) loadP((i + 2) * 64);
            compute(p);
        } else {
            stage(p, qa0, qa1, qb0, qb1, qb2, qb3);
            __syncthreads();
            if (i + 2 < NSTEP) loadQ((i + 2) * 64);
            compute(p);
        }
        p ^= 1;
    }
    const int er = (lane >> 4) * 4;
    const int ec = lane & 15;
    auto emit = [&](const f32x4& A, int mi, int ni) {
        #pragma unroll
        for (int r = 0; r < 4; ++r) {
            int m = m0 + mi * 16 + er + r;
            int n = n0 + wc + ni * 16 + ec;
            float v = A[r];
            if (EPI == 0) {
                v = lrelu(v + bias[n]);
                u16 h = f2bf(v);
                u16* p2 = (u16*)Cout + (size_t)m * ldc + n;
                p2[0] = h; p2[256] = f2bf(v - bf2f(h));
            } else if (EPI == 1) {
                if (n < N) ((float*)Cout)[(size_t)m * ldc + n] = v + bias[n];
            } else {
                float* cf = (float*)Cout + (size_t)blockIdx.z * sCz;
                cf[(size_t)m * ldc + n] = v;
            }
        }
    };
    emit(acc00, 0, 0); emit(acc01, 0, 1); emit(acc10, 1, 0); emit(acc11, 1, 1);
}

// ---------------- fused scan: chunk sums + serial prefix (LDS) + sincos + pair writes --
// grid (B_, 17), block 256 = 16 k (tid&15, fast) x 16 chunks (tid>>4).
// kg<16: k = kg*16 + (tid&15). kg==16: k=256 for (tid&15)==0; other threads zero pads.
// Prefix = serial sum over chunks 0..c-1 in order -> bit-identical to two-pass scan.
__global__ __launch_bounds__(256) void scanf_kernel(
    const float* __restrict__ raw, const float* __restrict__ noise,
    u16* __restrict__ ABe, u16* __restrict__ ABo)
{
    int b = blockIdx.x;
    int kg = blockIdx.y;
    int tid = threadIdx.x;
    int kl = tid & 15;
    int chunk = tid >> 4;
    bool active;
    int k;
    if (kg < 16) { k = kg * 16 + kl; active = true; }
    else         { k = 256;          active = (kl == 0); }

    __shared__ double ss[256];
    float dj[8], mj[8];
    double s = 0.0;
    float kf = (float)k * (PI_ / 256.f);
    int f0 = chunk * 8;
    if (active) {
        #pragma unroll
        for (int j = 0; j < 8; ++j) {
            size_t row = (size_t)(b * NF_ + f0 + j);
            float2 v = *(const float2*)(raw + row * TC_ + 2 * k);
            dj[j] = (1.f + v.y * noise[row * NC_ + k]) * kf;
            mj[j] = fabsf(v.x);
            s += (double)dj[j];
        }
    }
    ss[tid] = s;
    __syncthreads();
    if (active) {
        double p = 0.0;
        for (int cc = 0; cc < chunk; ++cc)
            p += ss[cc * 16 + kl];           // serial, order-preserving prefix
        int half = k >> 1;
        bool even = (k & 1) == 0;
        int ccol = half;
        int scol = even ? (129 + half) : (128 + half);
        u16* dst = even ? ABe : ABo;
        #pragma unroll
        for (int j = 0; j < 8; ++j) {
            p += (double)dj[j];
            float sn, cs;
            sincosf((float)p, &sn, &cs);
            float a = mj[j] * cs, bb = mj[j] * sn;
            u16* pr = dst + (size_t)(b * NF_ + f0 + j) * PIRW_;
            u16 ha = f2bf(a);
            pr[ccol] = ha; pr[SEGI_ + ccol] = f2bf(a - bf2f(ha));
            u16 hb = f2bf(bb);
            pr[scol] = hb; pr[SEGI_ + scol] = f2bf(bb - bf2f(hb));
        }
    } else {
        // pad zeroing (kg==16, kl!=0): 240 threads cover 252 pad columns x 128 rows
        int t = chunk * 15 + kl - 1;        // 0..239
        for (int idx = t; idx < 252; idx += 240) {
            int col;
            u16* base;
            if (idx < 62)       { col = 258 + idx;                 base = ABe; }
            else if (idx < 124) { col = SEGI_ + 258 + (idx - 62);  base = ABe; }
            else if (idx < 188) { col = 256 + (idx - 124);         base = ABo; }
            else                { col = SEGI_ + 256 + (idx - 188); base = ABo; }
            for (int f = 0; f < NF_; ++f)
                base[(size_t)(b * NF_ + f) * PIRW_ + col] = 0;
        }
    }
}

// ---------------- conv2: sparse conv with inline OLA; non-temporal out stores ---------
__global__ __launch_bounds__(256) void conv2_kernel(const float* __restrict__ E,
                                                    const float* __restrict__ O,
                                                    const int* __restrict__ cnt,
                                                    const float2* __restrict__ taps,
                                                    float* __restrict__ out) {
    int be = blockIdx.y;
    int b = be >> 4;
    int n = cnt[be];
    int t = blockIdx.x * 2048 + (int)threadIdx.x * 8;
    int r0 = t & 255;
    float hr[8], hr2[8];
    #pragma unroll
    for (int j = 0; j < 8; ++j) {
        float cj = cosf((float)(r0 + j) * (PI_ / 256.f));
        hr[j]  = 0.5f - 0.5f * cj;
        hr2[j] = 0.5f + 0.5f * cj;
    }
    float acc[8] = {};
    for (int i = 0; i < n; ++i) {
        float2 ka = taps[(size_t)be * NF_ + i];
        int s0 = t - ((int)ka.x << 8);
        if (s0 < 0) continue;
        float amp = ka.y;
        int q = s0 >> 8;
        size_t row = (size_t)(b * NF_ + q) * 256 + r0;
        float4 e0 = *(const float4*)(E + row);
        float4 e1 = *(const float4*)(E + row + 4);
        float4 o0 = *(const float4*)(O + row);
        float4 o1 = *(const float4*)(O + row + 4);
        float sv[8];
        sv[0] = hr[0] * (e0.x + o0.x); sv[1] = hr[1] * (e0.y + o0.y);
        sv[2] = hr[2] * (e0.z + o0.z); sv[3] = hr[3] * (e0.w + o0.w);
        sv[4] = hr[4] * (e1.x + o1.x); sv[5] = hr[5] * (e1.y + o1.y);
        sv[6] = hr[6] * (e1.z + o1.z); sv[7] = hr[7] * (e1.w + o1.w);
        if (q > 0) {
            float4 pe0 = *(const float4*)(E + row - 256);
            float4 pe1 = *(const float4*)(E + row - 252);
            float4 po0 = *(const float4*)(O + row - 256);
            float4 po1 = *(const float4*)(O + row - 252);
            sv[0] += hr2[0] * (pe0.x - po0.x); sv[1] += hr2[1] * (pe0.y - po0.y);
            sv[2] += hr2[2] * (pe0.z - po0.z); sv[3] += hr2[3] * (pe0.w - po0.w);
            sv[4] += hr2[4] * (pe1.x - po1.x); sv[5] += hr2[5] * (pe1.y - po1.y);
            sv[6] += hr2[6] * (pe1.z - po1.z); sv[7] += hr2[7] * (pe1.w - po1.w);
        }
        #pragma unroll
        for (int j = 0; j < 8; ++j) acc[j] += amp * sv[j];
    }
    float* op = out + (size_t)be * NS_ + t;
    f32x4 w0v = {acc[0], acc[1], acc[2], acc[3]};
    f32x4 w1v = {acc[4], acc[5], acc[6], acc[7]};
    __builtin_nontemporal_store(w0v, (f32x4*)op);
    __builtin_nontemporal_store(w1v, (f32x4*)(op + 4));
}

extern "C" void kernel_launch(void* const* d_in, const int* in_sizes, int n_in,
                              void* d_out, int out_size, void* d_ws, size_t ws_size,
                              hipStream_t stream) {
    const float* param  = (const float*)d_in[0];
    const float* times  = (const float*)d_in[1];
    const float* noise  = (const float*)d_in[2];
    const float* pos    = (const float*)d_in[3];
    const float* proj_w = (const float*)d_in[4];
    const float* proj_b = (const float*)d_in[5];
    const float* w0 = (const float*)d_in[6];
    const float* b0 = (const float*)d_in[7];
    const float* w1 = (const float*)d_in[8];
    const float* b1 = (const float*)d_in[9];
    const float* w2 = (const float*)d_in[10];
    const float* b2 = (const float*)d_in[11];
    const float* w_out = (const float*)d_in[12];
    const float* b_out = (const float*)d_in[13];
    float* out = (float*)d_out;
    float* ws = (float*)d_ws;

    // ws layout — cursor in FLOAT units; u16 buffers consume (u16_count/2) floats.
    constexpr size_t U_F    = 32 * 256;
    constexpr size_t V_F    = 128 * 256;
    constexpr size_t HP_F   = (size_t)ROWS_ * PMLW_ / 2;    // 1,048,576 per buffer
    constexpr size_t W_F    = (size_t)256 * PMLW_ / 2;      //    65,536
    constexpr size_t WO_F   = (size_t)576 * PMLW_ / 2;      //   147,456
    constexpr size_t RAW_F  = (size_t)ROWS_ * TC_;          // 2,105,344
    constexpr size_t ABP_F  = 2 * (size_t)ROWS_ * PIRW_ / 2;// 2,621,440
    constexpr size_t TTP_F  = 2 * (size_t)256 * PIRW_ / 2;  //   163,840
    constexpr size_t EO_F   = 2 * (size_t)ROWS_ * 256;      // 2,097,152

    size_t cur = 0;
    float* U    = ws + cur;                 cur += U_F;
    float* V    = ws + cur;                 cur += V_F;
    u16*  H1p   = (u16*)(ws + cur);         cur += HP_F;
    u16*  H2p   = (u16*)(ws + cur);         cur += HP_F;
    u16*  H3p   = (u16*)(ws + cur);         cur += HP_F;
    u16*  W1p   = (u16*)(ws + cur);         cur += W_F;
    u16*  W2p   = (u16*)(ws + cur);         cur += W_F;
    u16*  WOp   = (u16*)(ws + cur);         cur += WO_F;
    float* RAW  = ws + cur;                 cur += RAW_F;
    u16*  ABP   = (u16*)(ws + cur);         cur += ABP_F;
    u16*  ABe   = ABP;
    u16*  ABo   = ABP + (size_t)ROWS_ * PIRW_;
    u16*  TTP   = (u16*)(ws + cur);         cur += TTP_F;
    float* EO   = ws + cur;                 cur += EO_F;
    int*   CNT  = (int*)(ws + cur);         cur += 512;
    float2* TAPS = (float2*)(ws + cur);     // 512*128 float2

    // 1) fused prep: pair table (LUT) + weight pairs + taps + U + V
    prep_kernel<<<3040, 256, 0, stream>>>(param, proj_w, proj_b, pos, w0, w1, w2, w_out,
                                          times, TTP, W1p, W2p, WOp, CNT, TAPS, U, V);
    // 2) fuse1: H1 pair = lrelu(U[b]+V[f]+b0)
    fuse1_kernel<<<ROWS_ * CH_ / 256, 256, 0, stream>>>(U, V, b0, H1p);
    // 3) MLP layers 2,3 (bf16-split MFMA on pair buffers)
    mfgemm<0, K3MLP_, SEGM_><<<dim3(4, 128, 1), 128, 0, stream>>>(H1p, W1p, b1, H2p, 256,
                                                                  PMLW_, PMLW_, PMLW_, 0, 0, 0);
    mfgemm<0, K3MLP_, SEGM_><<<dim3(4, 128, 1), 128, 0, stream>>>(H2p, W2p, b2, H3p, 256,
                                                                  PMLW_, PMLW_, PMLW_, 0, 0, 0);
    // 4) output layer -> RAW fp32 (bias, N=514 guarded)
    mfgemm<1, K3MLP_, SEGM_><<<dim3(9, 128, 1), 128, 0, stream>>>(H3p, WOp, b_out, RAW, TC_,
                                                                  PMLW_, PMLW_, TC_, 0, 0, 0);
    // 5) fused phase scan (chunk sums in regs, serial LDS prefix, pads inline)
    scanf_kernel<<<dim3(B_, 17), 256, 0, stream>>>(RAW, noise, ABe, ABo);
    // 6) parity irfft (z-batched): EO[z] = AB[z] @ Tt[z]^T
    mfgemm<2, K3IR_, SEGI_><<<dim3(4, 128, 2), 128, 0, stream>>>(ABP, TTP, nullptr, EO, 256,
                                                                 PIRW_, PIRW_, 256,
                                                                 (size_t)ROWS_ * PIRW_,
                                                                 (size_t)256 * PIRW_,
                                                                 (size_t)ROWS_ * 256);
    // 7) sparse conv with inline overlap-add/hann -> out (non-temporal stores)
    dim3 gC(NS_ / 2048, B_ * NE_);
    conv2_kernel<<<gC, 256, 0, stream>>>(EO, EO + (size_t)ROWS_ * 256, CNT, TAPS, out);
}

// Round 16
// 93.770 us; speedup vs baseline: 2.9729x; 1.0011x over previous
//
#include <hip/hip_runtime.h>
#include <cstddef>

typedef unsigned short u16;
typedef __bf16 bf16x8 __attribute__((ext_vector_type(8)));
typedef float f32x4 __attribute__((ext_vector_type(4)));

// Problem constants
constexpr int B_   = 32;
constexpr int CTX_ = 128;
constexpr int NF_  = 128;     // frames
constexpr int NS_  = 32768;   // samples
constexpr int NE_  = 16;      // events
constexpr int CH_  = 256;
constexpr int NC_  = 257;     // coeffs
constexpr int TC_  = 514;     // 2*coeffs
constexpr int ROWS_ = B_ * NF_;  // 4096
constexpr int K3MLP_ = 768;      // 3*256 (logical triplet K)
constexpr int SEGM_ = 256;       // MLP pair-plane width
constexpr int K3IR_ = 960;       // 3*320 (logical triplet K, irfft)
constexpr int SEGI_ = 320;       // irfft pair-plane width (content 258/256 + zeros)
constexpr int PIRW_ = 2 * SEGI_; // 640 u16 per AB row
constexpr int PMLW_ = 2 * SEGM_; // 512 u16 per H/W row
constexpr float PI_ = 3.14159265358979323846f;

__device__ __forceinline__ float lrelu(float v) { return v > 0.f ? v : 0.2f * v; }
__device__ __forceinline__ u16 f2bf(float x) {
    unsigned u = __float_as_uint(x);
    return (u16)((u + 0x7FFFu + ((u >> 16) & 1u)) >> 16);
}
__device__ __forceinline__ float bf2f(u16 h) { return __uint_as_float(((unsigned)h) << 16); }

// ============ prep: table(pair,LUT) | weights(pair) | compact | U | V ============
// [0,1280): irfft pair table  [1280,2368): weight pairs
// [2368,2880): tap compaction [2880,2912): U rows  [2912,3040): V rows
__global__ __launch_bounds__(256) void prep_kernel(
    const float* __restrict__ param, const float* __restrict__ pw,
    const float* __restrict__ pb, const float* __restrict__ pos,
    const float* __restrict__ w0, const float* __restrict__ w1,
    const float* __restrict__ w2, const float* __restrict__ wo,
    const float* __restrict__ times,
    u16* __restrict__ Tt, u16* __restrict__ W1p, u16* __restrict__ W2p,
    u16* __restrict__ WOp, int* __restrict__ cnt, float2* __restrict__ taps,
    float* __restrict__ U, float* __restrict__ V)
{
    int blk = blockIdx.x;
    int tid = threadIdx.x;
    if (blk < 1280) {
        // ---- irfft pair table via 512-entry cos LUT ----
        __shared__ float lut[512];
        lut[tid]       = cosf((float)tid * (PI_ / 256.f));
        lut[tid + 256] = cosf((float)(tid + 256) * (PI_ / 256.f));
        __syncthreads();
        int idx = blk * 256 + tid;              // < 2*256*640
        int z = idx / (256 * PIRW_);
        int r = idx - z * (256 * PIRW_);
        int n = r / PIRW_, c = r - n * PIRW_;
        bool hiplane = c < SEGI_;
        int j = hiplane ? c : c - SEGI_;
        float val = 0.f;
        if (z == 0) {
            if (j < 129) {
                int k = 2 * j;
                float w = (k == 0 || k == 256) ? 1.f : 2.f;
                int m = (k * n) & 511;
                val = w * (1.f / 512.f) * lut[m];
            } else if (j < 258) {
                int kk = 2 * (j - 129);
                float w = (kk == 0 || kk == 256) ? 1.f : 2.f;
                int m = (kk * n) & 511;
                val = -w * (1.f / 512.f) * lut[(m - 128) & 511];   // sin
            }
        } else {
            if (j < 128) {
                int k = 2 * j + 1;
                int m = (k * n) & 511;
                val = 2.f * (1.f / 512.f) * lut[m];
            } else if (j < 256) {
                int kk = 2 * (j - 128) + 1;
                int m = (kk * n) & 511;
                val = -2.f * (1.f / 512.f) * lut[(m - 128) & 511]; // sin
            }
        }
        u16 h = f2bf(val);
        Tt[idx] = hiplane ? h : f2bf(val - bf2f(h));
    } else if (blk < 2368) {
        // ---- weight pairs (hi|lo planar) ----
        int row = blk - 1280;        // 0..1087
        int k = tid;
        float v;
        u16* p;
        if (row < 256) {
            v = w1[row * 256 + k];
            p = W1p + (size_t)row * PMLW_;
        } else if (row < 512) {
            v = w2[(row - 256) * 256 + k];
            p = W2p + (size_t)(row - 256) * PMLW_;
        } else {
            int n = row - 512;       // 0..575, valid < 514
            v = (n < TC_) ? wo[n * 256 + k] : 0.f;
            p = WOp + (size_t)n * PMLW_;
        }
        u16 h = f2bf(v);
        p[k] = h; p[256 + k] = f2bf(v - bf2f(h));
    } else if (blk < 2880) {
        // ---- tap compaction ----
        int be = blk - 2368;
        __shared__ int c;
        if (tid == 0) c = 0;
        __syncthreads();
        if (tid < NF_) {
            float v = times[(size_t)be * NF_ + tid];
            if (v != 0.f) {
                int slot = atomicAdd(&c, 1);
                taps[(size_t)be * NF_ + slot] = make_float2((float)tid, v);
            }
        }
        __syncthreads();
        if (tid == 0) cnt[be] = c;
    } else if (blk < 2912) {
        // ---- U rows: recompute y0[b] in LDS, then U[b][n] = y0 . w0[n] ----
        int b = blk - 2880;      // 0..31
        __shared__ float ly[256];
        {
            const float* pr = param + b * CTX_;
            const float* wr = pw + tid * CTX_;
            float s = 0.f;
            #pragma unroll 4
            for (int j = 0; j < CTX_; ++j) s += pr[j] * wr[j];
            ly[tid] = s + pb[tid];
        }
        __syncthreads();
        {
            const float* wn = w0 + tid * CH_;
            float s = 0.f;
            #pragma unroll 4
            for (int c2 = 0; c2 < CH_; ++c2) s += ly[c2] * wn[c2];
            U[b * CH_ + tid] = s;
        }
    } else {
        // ---- V rows: V[f][n] = pos[f] . w0[n] ----
        int f = blk - 2912;      // 0..127
        const float* pf = pos + f * CH_;
        const float* wn = w0 + tid * CH_;
        float s = 0.f;
        #pragma unroll 4
        for (int c2 = 0; c2 < CH_; ++c2) s += pf[c2] * wn[c2];
        V[f * CH_ + tid] = s;
    }
}

// ---------------- fuse1: H1 pair = lrelu(U[b] + V[f] + b0) ----------------
__global__ void fuse1_kernel(const float* __restrict__ U, const float* __restrict__ V,
                             const float* __restrict__ b0, u16* __restrict__ Hp) {
    int idx = blockIdx.x * 256 + threadIdx.x;   // 4096*256
    int c = idx & 255;
    int row = idx >> 8;
    int b = row >> 7, f = row & 127;
    float v = lrelu(U[b * CH_ + c] + V[f * CH_ + c] + b0[c]);
    u16 h = f2bf(v);
    u16* p = Hp + (size_t)row * PMLW_;
    p[c] = h; p[256 + c] = f2bf(v - bf2f(h));
}

// ---------------- mfgemm: C = A3 @ B3^T, bf16-split MFMA on PAIR buffers ----------
// Logical triplet A=[Ah|Al|Ah], B=[Bh|Bh|Bl] with plane width SEG; global buffers
// store only [hi|lo]; prefetch offsets remapped at compile time:
//   kA(kt) = kt>=2*SEG ? kt-2*SEG : kt ;  kB(kt) = kt>=SEG ? kt-SEG : kt.
// 32x64 tile, 128 threads, depth-2 prefetch, double-buffered LDS (24KB).
// EPI 0: bias+lrelu -> bf16 pair (ldc=512); EPI 1: bias -> fp32 (N-guarded);
// EPI 2: plain fp32 (z-batched).
template<int EPI, int K3, int SEG>
__global__ __launch_bounds__(128) void mfgemm(
    const u16* __restrict__ A3, const u16* __restrict__ B3,
    const float* __restrict__ bias, void* __restrict__ Cout,
    int N, int lda, int ldb, int ldc,
    size_t sAz, size_t sBz, size_t sCz)
{
    constexpr int NSTEP = K3 / 64;
    A3 += (size_t)blockIdx.z * sAz;
    B3 += (size_t)blockIdx.z * sBz;
    const int tid = threadIdx.x;
    const int m0 = blockIdx.y * 32, n0 = blockIdx.x * 64;
    __shared__ __align__(16) u16 Als[2 * 32 * 64];   //  8KB
    __shared__ __align__(16) u16 Bls[2 * 64 * 64];   // 16KB
    const int sr = tid >> 2;
    const int sc = (tid & 3) * 16;
    const u16* ga  = A3 + (size_t)(m0 + sr) * lda + sc;
    const u16* gb0 = B3 + (size_t)(n0 + sr) * ldb + sc;
    const u16* gb1 = B3 + (size_t)(n0 + 32 + sr) * ldb + sc;
    const int xr = (sr & 7) << 4;
    const int loA0 = sr * 128 + ((sc * 2) ^ xr);
    const int loA1 = sr * 128 + ((sc * 2 + 16) ^ xr);
    const int loB2 = (sr + 32) * 128 + ((sc * 2) ^ xr);
    const int loB3 = (sr + 32) * 128 + ((sc * 2 + 16) ^ xr);
    const int wv = tid >> 6, lane = tid & 63;
    const int wc = wv * 32;
    const int lr = lane & 15;
    const int lkb = (lane >> 4) * 16;
    const int xf = (lr & 7) << 4;
    const int raf0 = lr * 128, raf1 = (16 + lr) * 128;
    const int rbf0 = (wc + lr) * 128, rbf1 = (wc + 16 + lr) * 128;
    f32x4 acc00 = {0.f, 0.f, 0.f, 0.f}, acc01 = acc00, acc10 = acc00, acc11 = acc00;

    uint4 pa0, pa1, pb0, pb1, pb2, pb3;   // set P
    uint4 qa0, qa1, qb0, qb1, qb2, qb3;   // set Q
    auto kA = [](int kt) { return kt >= 2 * SEG ? kt - 2 * SEG : kt; };
    auto kB = [](int kt) { return kt >= SEG ? kt - SEG : kt; };
    auto loadP = [&](int kt) {
        int a = kA(kt), b = kB(kt);
        pa0 = *(const uint4*)(ga + a);  pa1 = *(const uint4*)(ga + a + 8);
        pb0 = *(const uint4*)(gb0 + b); pb1 = *(const uint4*)(gb0 + b + 8);
        pb2 = *(const uint4*)(gb1 + b); pb3 = *(const uint4*)(gb1 + b + 8);
    };
    auto loadQ = [&](int kt) {
        int a = kA(kt), b = kB(kt);
        qa0 = *(const uint4*)(ga + a);  qa1 = *(const uint4*)(ga + a + 8);
        qb0 = *(const uint4*)(gb0 + b); qb1 = *(const uint4*)(gb0 + b + 8);
        qb2 = *(const uint4*)(gb1 + b); qb3 = *(const uint4*)(gb1 + b + 8);
    };
    auto compute = [&](int p) {
        const char* pa = (const char*)Als + p * 4096;
        const char* pb = (const char*)Bls + p * 8192;
        #pragma unroll
        for (int s = 0; s < 2; ++s) {
            int kb = (s * 64 + lkb) ^ xf;
            bf16x8 a0 = *(const bf16x8*)(pa + raf0 + kb);
            bf16x8 a1 = *(const bf16x8*)(pa + raf1 + kb);
            bf16x8 b0 = *(const bf16x8*)(pb + rbf0 + kb);
            bf16x8 b1 = *(const bf16x8*)(pb + rbf1 + kb);
            acc00 = __builtin_amdgcn_mfma_f32_16x16x32_bf16(a0, b0, acc00, 0, 0, 0);
            acc01 = __builtin_amdgcn_mfma_f32_16x16x32_bf16(a0, b1, acc01, 0, 0, 0);
            acc10 = __builtin_amdgcn_mfma_f32_16x16x32_bf16(a1, b0, acc10, 0, 0, 0);
            acc11 = __builtin_amdgcn_mfma_f32_16x16x32_bf16(a1, b1, acc11, 0, 0, 0);
        }
    };
    auto stage = [&](int p, const uint4& a0, const uint4& a1, const uint4& b0,
                     const uint4& b1, const uint4& b2, const uint4& b3) {
        char* ab = (char*)Als + p * 4096;
        char* bb = (char*)Bls + p * 8192;
        *(uint4*)(ab + loA0) = a0; *(uint4*)(ab + loA1) = a1;
        *(uint4*)(bb + loA0) = b0; *(uint4*)(bb + loA1) = b1;
        *(uint4*)(bb + loB2) = b2; *(uint4*)(bb + loB3) = b3;
    };
    loadP(0);
    if (NSTEP > 1) loadQ(64);
    int p = 0;
    #pragma unroll
    for (int i = 0; i < NSTEP; ++i) {
        if ((i & 1) == 0) {
            stage(p, pa0, pa1, pb0, pb1, pb2, pb3);
            __syncthreads();
            if (i + 2 < NSTEP) loadP((i + 2) * 64);
            compute(p);
        } else {
            stage(p, qa0, qa1, qb0, qb1, qb2, qb3);
            __syncthreads();
            if (i + 2 < NSTEP) loadQ((i + 2) * 64);
            compute(p);
        }
        p ^= 1;
    }
    const int er = (lane >> 4) * 4;
    const int ec = lane & 15;
    auto emit = [&](const f32x4& A, int mi, int ni) {
        #pragma unroll
        for (int r = 0; r < 4; ++r) {
            int m = m0 + mi * 16 + er + r;
            int n = n0 + wc + ni * 16 + ec;
            float v = A[r];
            if (EPI == 0) {
                v = lrelu(v + bias[n]);
                u16 h = f2bf(v);
                u16* p2 = (u16*)Cout + (size_t)m * ldc + n;
                p2[0] = h; p2[256] = f2bf(v - bf2f(h));
            } else if (EPI == 1) {
                if (n < N) ((float*)Cout)[(size_t)m * ldc + n] = v + bias[n];
            } else {
                float* cf = (float*)Cout + (size_t)blockIdx.z * sCz;
                cf[(size_t)m * ldc + n] = v;
            }
        }
    };
    emit(acc00, 0, 0); emit(acc01, 0, 1); emit(acc10, 1, 0); emit(acc11, 1, 1);
}

// ---------------- fused scan: chunk sums + serial prefix (LDS) + sincos + pair writes --
// grid (B_, 17), block 256 = 16 k (tid&15, fast) x 16 chunks (tid>>4).
// kg<16: k = kg*16 + (tid&15). kg==16: k=256 for (tid&15)==0; other threads zero pads.
// Prefix = serial sum over chunks 0..c-1 in order -> bit-identical to two-pass scan.
__global__ __launch_bounds__(256) void scanf_kernel(
    const float* __restrict__ raw, const float* __restrict__ noise,
    u16* __restrict__ ABe, u16* __restrict__ ABo)
{
    int b = blockIdx.x;
    int kg = blockIdx.y;
    int tid = threadIdx.x;
    int kl = tid & 15;
    int chunk = tid >> 4;
    bool active;
    int k;
    if (kg < 16) { k = kg * 16 + kl; active = true; }
    else         { k = 256;          active = (kl == 0); }

    __shared__ double ss[256];
    float dj[8], mj[8];
    double s = 0.0;
    float kf = (float)k * (PI_ / 256.f);
    int f0 = chunk * 8;
    if (active) {
        #pragma unroll
        for (int j = 0; j < 8; ++j) {
            size_t row = (size_t)(b * NF_ + f0 + j);
            float2 v = *(const float2*)(raw + row * TC_ + 2 * k);
            dj[j] = (1.f + v.y * noise[row * NC_ + k]) * kf;
            mj[j] = fabsf(v.x);
            s += (double)dj[j];
        }
    }
    ss[tid] = s;
    __syncthreads();
    if (active) {
        double p = 0.0;
        for (int cc = 0; cc < chunk; ++cc)
            p += ss[cc * 16 + kl];           // serial, order-preserving prefix
        int half = k >> 1;
        bool even = (k & 1) == 0;
        int ccol = half;
        int scol = even ? (129 + half) : (128 + half);
        u16* dst = even ? ABe : ABo;
        #pragma unroll
        for (int j = 0; j < 8; ++j) {
            p += (double)dj[j];
            float sn, cs;
            sincosf((float)p, &sn, &cs);
            float a = mj[j] * cs, bb = mj[j] * sn;
            u16* pr = dst + (size_t)(b * NF_ + f0 + j) * PIRW_;
            u16 ha = f2bf(a);
            pr[ccol] = ha; pr[SEGI_ + ccol] = f2bf(a - bf2f(ha));
            u16 hb = f2bf(bb);
            pr[scol] = hb; pr[SEGI_ + scol] = f2bf(bb - bf2f(hb));
        }
    } else {
        // pad zeroing (kg==16, kl!=0): 240 threads cover 252 pad columns x 128 rows
        int t = chunk * 15 + kl - 1;        // 0..239
        for (int idx = t; idx < 252; idx += 240) {
            int col;
            u16* base;
            if (idx < 62)       { col = 258 + idx;                 base = ABe; }
            else if (idx < 124) { col = SEGI_ + 258 + (idx - 62);  base = ABe; }
            else if (idx < 188) { col = 256 + (idx - 124);         base = ABo; }
            else                { col = SEGI_ + 256 + (idx - 188); base = ABo; }
            for (int f = 0; f < NF_; ++f)
                base[(size_t)(b * NF_ + f) * PIRW_ + col] = 0;
        }
    }
}

// ---------------- conv2: sparse conv + inline OLA; hann via LDS LUT; NT stores --------
__global__ __launch_bounds__(256) void conv2_kernel(const float* __restrict__ E,
                                                    const float* __restrict__ O,
                                                    const int* __restrict__ cnt,
                                                    const float2* __restrict__ taps,
                                                    float* __restrict__ out) {
    // 256-entry cos LUT: one cosf per thread (same expression as before -> bit-identical)
    __shared__ float clut[256];
    clut[threadIdx.x] = cosf((float)threadIdx.x * (PI_ / 256.f));
    __syncthreads();
    int be = blockIdx.y;
    int b = be >> 4;
    int n = cnt[be];
    int t = blockIdx.x * 2048 + (int)threadIdx.x * 8;
    int r0 = t & 255;
    float hr[8], hr2[8];
    #pragma unroll
    for (int j = 0; j < 8; ++j) {
        float cj = clut[r0 + j];
        hr[j]  = 0.5f - 0.5f * cj;
        hr2[j] = 0.5f + 0.5f * cj;
    }
    float acc[8] = {};
    for (int i = 0; i < n; ++i) {
        float2 ka = taps[(size_t)be * NF_ + i];
        int s0 = t - ((int)ka.x << 8);
        if (s0 < 0) continue;
        float amp = ka.y;
        int q = s0 >> 8;
        size_t row = (size_t)(b * NF_ + q) * 256 + r0;
        float4 e0 = *(const float4*)(E + row);
        float4 e1 = *(const float4*)(E + row + 4);
        float4 o0 = *(const float4*)(O + row);
        float4 o1 = *(const float4*)(O + row + 4);
        float sv[8];
        sv[0] = hr[0] * (e0.x + o0.x); sv[1] = hr[1] * (e0.y + o0.y);
        sv[2] = hr[2] * (e0.z + o0.z); sv[3] = hr[3] * (e0.w + o0.w);
        sv[4] = hr[4] * (e1.x + o1.x); sv[5] = hr[5] * (e1.y + o1.y);
        sv[6] = hr[6] * (e1.z + o1.z); sv[7] = hr[7] * (e1.w + o1.w);
        if (q > 0) {
            float4 pe0 = *(const float4*)(E + row - 256);
            float4 pe1 = *(const float4*)(E + row - 252);
            float4 po0 = *(const float4*)(O + row - 256);
            float4 po1 = *(const float4*)(O + row - 252);
            sv[0] += hr2[0] * (pe0.x - po0.x); sv[1] += hr2[1] * (pe0.y - po0.y);
            sv[2] += hr2[2] * (pe0.z - po0.z); sv[3] += hr2[3] * (pe0.w - po0.w);
            sv[4] += hr2[4] * (pe1.x - po1.x); sv[5] += hr2[5] * (pe1.y - po1.y);
            sv[6] += hr2[6] * (pe1.z - po1.z); sv[7] += hr2[7] * (pe1.w - po1.w);
        }
        #pragma unroll
        for (int j = 0; j < 8; ++j) acc[j] += amp * sv[j];
    }
    float* op = out + (size_t)be * NS_ + t;
    f32x4 w0v = {acc[0], acc[1], acc[2], acc[3]};
    f32x4 w1v = {acc[4], acc[5], acc[6], acc[7]};
    __builtin_nontemporal_store(w0v, (f32x4*)op);
    __builtin_nontemporal_store(w1v, (f32x4*)(op + 4));
}

extern "C" void kernel_launch(void* const* d_in, const int* in_sizes, int n_in,
                              void* d_out, int out_size, void* d_ws, size_t ws_size,
                              hipStream_t stream) {
    const float* param  = (const float*)d_in[0];
    const float* times  = (const float*)d_in[1];
    const float* noise  = (const float*)d_in[2];
    const float* pos    = (const float*)d_in[3];
    const float* proj_w = (const float*)d_in[4];
    const float* proj_b = (const float*)d_in[5];
    const float* w0 = (const float*)d_in[6];
    const float* b0 = (const float*)d_in[7];
    const float* w1 = (const float*)d_in[8];
    const float* b1 = (const float*)d_in[9];
    const float* w2 = (const float*)d_in[10];
    const float* b2 = (const float*)d_in[11];
    const float* w_out = (const float*)d_in[12];
    const float* b_out = (const float*)d_in[13];
    float* out = (float*)d_out;
    float* ws = (float*)d_ws;

    // ws layout — cursor in FLOAT units; u16 buffers consume (u16_count/2) floats.
    constexpr size_t U_F    = 32 * 256;
    constexpr size_t V_F    = 128 * 256;
    constexpr size_t HP_F   = (size_t)ROWS_ * PMLW_ / 2;    // 1,048,576 per buffer
    constexpr size_t W_F    = (size_t)256 * PMLW_ / 2;      //    65,536
    constexpr size_t WO_F   = (size_t)576 * PMLW_ / 2;      //   147,456
    constexpr size_t RAW_F  = (size_t)ROWS_ * TC_;          // 2,105,344
    constexpr size_t ABP_F  = 2 * (size_t)ROWS_ * PIRW_ / 2;// 2,621,440
    constexpr size_t TTP_F  = 2 * (size_t)256 * PIRW_ / 2;  //   163,840
    constexpr size_t EO_F   = 2 * (size_t)ROWS_ * 256;      // 2,097,152

    size_t cur = 0;
    float* U    = ws + cur;                 cur += U_F;
    float* V    = ws + cur;                 cur += V_F;
    u16*  H1p   = (u16*)(ws + cur);         cur += HP_F;
    u16*  H2p   = (u16*)(ws + cur);         cur += HP_F;
    u16*  H3p   = (u16*)(ws + cur);         cur += HP_F;
    u16*  W1p   = (u16*)(ws + cur);         cur += W_F;
    u16*  W2p   = (u16*)(ws + cur);         cur += W_F;
    u16*  WOp   = (u16*)(ws + cur);         cur += WO_F;
    float* RAW  = ws + cur;                 cur += RAW_F;
    u16*  ABP   = (u16*)(ws + cur);         cur += ABP_F;
    u16*  ABe   = ABP;
    u16*  ABo   = ABP + (size_t)ROWS_ * PIRW_;
    u16*  TTP   = (u16*)(ws + cur);         cur += TTP_F;
    float* EO   = ws + cur;                 cur += EO_F;
    int*   CNT  = (int*)(ws + cur);         cur += 512;
    float2* TAPS = (float2*)(ws + cur);     // 512*128 float2

    // 1) fused prep: pair table (LUT) + weight pairs + taps + U + V
    prep_kernel<<<3040, 256, 0, stream>>>(param, proj_w, proj_b, pos, w0, w1, w2, w_out,
                                          times, TTP, W1p, W2p, WOp, CNT, TAPS, U, V);
    // 2) fuse1: H1 pair = lrelu(U[b]+V[f]+b0)
    fuse1_kernel<<<ROWS_ * CH_ / 256, 256, 0, stream>>>(U, V, b0, H1p);
    // 3) MLP layers 2,3 (bf16-split MFMA on pair buffers)
    mfgemm<0, K3MLP_, SEGM_><<<dim3(4, 128, 1), 128, 0, stream>>>(H1p, W1p, b1, H2p, 256,
                                                                  PMLW_, PMLW_, PMLW_, 0, 0, 0);
    mfgemm<0, K3MLP_, SEGM_><<<dim3(4, 128, 1), 128, 0, stream>>>(H2p, W2p, b2, H3p, 256,
                                                                  PMLW_, PMLW_, PMLW_, 0, 0, 0);
    // 4) output layer -> RAW fp32 (bias, N=514 guarded)
    mfgemm<1, K3MLP_, SEGM_><<<dim3(9, 128, 1), 128, 0, stream>>>(H3p, WOp, b_out, RAW, TC_,
                                                                  PMLW_, PMLW_, TC_, 0, 0, 0);
    // 5) fused phase scan (chunk sums in regs, serial LDS prefix, pads inline)
    scanf_kernel<<<dim3(B_, 17), 256, 0, stream>>>(RAW, noise, ABe, ABo);
    // 6) parity irfft (z-batched): EO[z] = AB[z] @ Tt[z]^T
    mfgemm<2, K3IR_, SEGI_><<<dim3(4, 128, 2), 128, 0, stream>>>(ABP, TTP, nullptr, EO, 256,
                                                                 PIRW_, PIRW_, 256,
                                                                 (size_t)ROWS_ * PIRW_,
                                                                 (size_t)256 * PIRW_,
                                                                 (size_t)ROWS_ * 256);
    // 7) sparse conv + inline OLA (hann LUT) -> out (non-temporal stores)
    dim3 gC(NS_ / 2048, B_ * NE_);
    conv2_kernel<<<gC, 256, 0, stream>>>(EO, EO + (size_t)ROWS_ * 256, CNT, TAPS, out);
}